// Round 2
// baseline (2379.840 us; speedup 1.0000x reference)
//
#include <hip/hip_runtime.h>

// Problem constants
#define NN 100000
#define NE 1600000
#define DIN 32
#define DE 16
#define HC 64
#define NL 4
#define MHC 128
#define OUTC 10
#define NG 128

// ---- CSR build ----
__global__ __launch_bounds__(256) void k_deg(const int* __restrict__ dst, int* __restrict__ deg) {
  int e = blockIdx.x * 256 + threadIdx.x;
  if (e < NE) atomicAdd(&deg[dst[e]], 1);
}

__global__ __launch_bounds__(1024) void k_scan1(const int* __restrict__ deg, int* __restrict__ offs, int* __restrict__ bsum) {
  __shared__ int s[1024];
  int t = threadIdx.x;
  int i = blockIdx.x * 1024 + t;
  int v = (i < NN) ? deg[i] : 0;
  s[t] = v; __syncthreads();
  for (int d = 1; d < 1024; d <<= 1) {
    int x = 0;
    if (t >= d) x = s[t - d];
    __syncthreads();
    if (t >= d) s[t] += x;
    __syncthreads();
  }
  if (i < NN) offs[i] = s[t] - v;      // exclusive within block
  if (t == 1023) bsum[blockIdx.x] = s[t];
}

__global__ __launch_bounds__(128) void k_scan2(int* __restrict__ bsum, int nb) {
  __shared__ int s[128];
  int t = threadIdx.x;
  int v = (t < nb) ? bsum[t] : 0;
  s[t] = v; __syncthreads();
  for (int d = 1; d < 128; d <<= 1) {
    int x = 0;
    if (t >= d) x = s[t - d];
    __syncthreads();
    if (t >= d) s[t] += x;
    __syncthreads();
  }
  if (t < nb) bsum[t] = s[t] - v;      // exclusive
}

__global__ __launch_bounds__(256) void k_scan3(int* __restrict__ offs, const int* __restrict__ bsum, int* __restrict__ cur) {
  int i = blockIdx.x * 256 + threadIdx.x;
  if (i < NN) {
    int o = offs[i] + bsum[i >> 10];
    offs[i] = o;
    cur[i] = o;
  }
}

__global__ __launch_bounds__(256) void k_fill(const int* __restrict__ src, const int* __restrict__ dst,
                                              int* __restrict__ cur, int2* __restrict__ csr) {
  int e = blockIdx.x * 256 + threadIdx.x;
  if (e < NE) {
    int d = dst[e];
    int pos = atomicAdd(&cur[d], 1);
    csr[pos] = make_int2(src[e], e);
  }
}

// ---- w2 transpose: w2t[mat][c1][c2] = w2[mat][c2][c1] ----
__global__ __launch_bounds__(256) void k_tr(const float* __restrict__ l0w2, const float* __restrict__ w2,
                                            float* __restrict__ w2t) {
  int id = blockIdx.x * 256 + threadIdx.x;   // 4 * 4096
  int mat = id >> 12;
  int j = id & 4095;
  int c1 = j >> 6, c2 = j & 63;
  const float* s = (mat == 0) ? l0w2 : (w2 + (size_t)(mat - 1) * 4096);
  w2t[mat * 4096 + j] = s[c2 * 64 + c1];
}

// ---- edge aggregation: one wave per node, lane = channel ----
template<int C>
__global__ __launch_bounds__(256) void k_edge(
    const int2* __restrict__ csr, const int* __restrict__ offs, const int* __restrict__ deg,
    const float* __restrict__ xsrc, const float* __restrict__ eattr,
    const float* __restrict__ ewf, const float* __restrict__ ebf,
    float* __restrict__ hpre)
{
  int gt = blockIdx.x * 256 + threadIdx.x;
  int node = gt >> 6;
  if (node >= NN) return;
  int lane = threadIdx.x & 63;
  constexpr int EP = 64 / C;
  int ep = lane / C;
  int c = lane % C;
  float w[16];
  const float4* wv = (const float4*)(ewf + c * 16);
  #pragma unroll
  for (int q = 0; q < 4; q++) {
    float4 t = wv[q];
    w[4*q] = t.x; w[4*q+1] = t.y; w[4*q+2] = t.z; w[4*q+3] = t.w;
  }
  float bc = ebf[c];
  int start = offs[node], n = deg[node];
  float acc = 0.f;
  for (int i = ep; i < n; i += EP) {
    int2 p = csr[start + i];
    const float4* ea = (const float4*)(eattr + (size_t)p.y * 16);
    float4 a0 = ea[0], a1 = ea[1], a2 = ea[2], a3 = ea[3];
    float el = bc;
    el = fmaf(a0.x, w[0],  el); el = fmaf(a0.y, w[1],  el);
    el = fmaf(a0.z, w[2],  el); el = fmaf(a0.w, w[3],  el);
    el = fmaf(a1.x, w[4],  el); el = fmaf(a1.y, w[5],  el);
    el = fmaf(a1.z, w[6],  el); el = fmaf(a1.w, w[7],  el);
    el = fmaf(a2.x, w[8],  el); el = fmaf(a2.y, w[9],  el);
    el = fmaf(a2.z, w[10], el); el = fmaf(a2.w, w[11], el);
    el = fmaf(a3.x, w[12], el); el = fmaf(a3.y, w[13], el);
    el = fmaf(a3.z, w[14], el); el = fmaf(a3.w, w[15], el);
    float xs = xsrc[(size_t)p.x * C + c];
    float m = xs + el;
    acc += fmaxf(m, 0.f);
  }
  if (EP == 2) acc += __shfl_xor(acc, 32);
  if (ep == 0) {
    hpre[(size_t)node * C + c] = xsrc[(size_t)node * C + c] + acc;
  }
}

// ---- fused node MLP: one thread per row, wave-uniform (s_load) weights ----
template<int CIN>
__global__ __launch_bounds__(256) void k_mlp(
    const float* __restrict__ hpre,
    const float* __restrict__ w1f, const float* __restrict__ b1f,
    const float* __restrict__ w2tf, const float* __restrict__ b2v,
    float* __restrict__ h2)
{
  int row = blockIdx.x * 256 + threadIdx.x;
  if (row >= NN) return;
  float hrow[CIN];
  const float4* hp = (const float4*)(hpre + (size_t)row * CIN);
  #pragma unroll
  for (int k = 0; k < CIN / 4; k++) {
    float4 v = hp[k];
    hrow[4*k] = v.x; hrow[4*k+1] = v.y; hrow[4*k+2] = v.z; hrow[4*k+3] = v.w;
  }
  float acc2[64];
  #pragma unroll
  for (int c = 0; c < 64; c++) acc2[c] = b2v[c];
  #pragma unroll 4
  for (int c1 = 0; c1 < 64; c1++) {
    float a = b1f[c1];
    #pragma unroll
    for (int k = 0; k < CIN; k++) a = fmaf(w1f[c1 * CIN + k], hrow[k], a);
    a = fmaxf(a, 0.f);
    #pragma unroll
    for (int c2 = 0; c2 < 64; c2++) acc2[c2] = fmaf(w2tf[c1 * 64 + c2], a, acc2[c2]);
  }
  float4* out = (float4*)(h2 + (size_t)row * 64);
  #pragma unroll
  for (int q = 0; q < 16; q++) {
    float4 v;
    v.x = fmaxf(acc2[4*q], 0.f);
    v.y = fmaxf(acc2[4*q+1], 0.f);
    v.z = fmaxf(acc2[4*q+2], 0.f);
    v.w = fmaxf(acc2[4*q+3], 0.f);
    out[q] = v;
  }
}

// ---- BN stats: coalesced float4 pass over h2 ----
__global__ __launch_bounds__(256) void k_stats(const float* __restrict__ h2,
                                               float* __restrict__ bns, float* __restrict__ bnq) {
  int c4 = threadIdx.x & 15, rg = threadIdx.x >> 4;
  float sx = 0, sy = 0, sz = 0, sw = 0;
  float qx = 0, qy = 0, qz = 0, qw = 0;
  for (int r = blockIdx.x * 16 + rg; r < NN; r += gridDim.x * 16) {
    float4 v = *(const float4*)(h2 + (size_t)r * 64 + c4 * 4);
    sx += v.x; sy += v.y; sz += v.z; sw += v.w;
    qx += v.x * v.x; qy += v.y * v.y; qz += v.z * v.z; qw += v.w * v.w;
  }
  __shared__ float4 ls[256], lq[256];
  ls[threadIdx.x] = make_float4(sx, sy, sz, sw);
  lq[threadIdx.x] = make_float4(qx, qy, qz, qw);
  __syncthreads();
  for (int d = 128; d >= 16; d >>= 1) {
    if ((int)threadIdx.x < d) {
      float4 a = ls[threadIdx.x], b = ls[threadIdx.x + d];
      ls[threadIdx.x] = make_float4(a.x + b.x, a.y + b.y, a.z + b.z, a.w + b.w);
      float4 c = lq[threadIdx.x], e = lq[threadIdx.x + d];
      lq[threadIdx.x] = make_float4(c.x + e.x, c.y + e.y, c.z + e.z, c.w + e.w);
    }
    __syncthreads();
  }
  if (threadIdx.x < 16) {
    float4 S = ls[threadIdx.x], Q = lq[threadIdx.x];
    int cb = threadIdx.x * 4;
    atomicAdd(&bns[cb], S.x);   atomicAdd(&bns[cb+1], S.y);
    atomicAdd(&bns[cb+2], S.z); atomicAdd(&bns[cb+3], S.w);
    atomicAdd(&bnq[cb], Q.x);   atomicAdd(&bnq[cb+1], Q.y);
    atomicAdd(&bnq[cb+2], Q.z); atomicAdd(&bnq[cb+3], Q.w);
  }
}

__global__ __launch_bounds__(64) void k_bnfin(const float* __restrict__ bns, const float* __restrict__ bnq,
                                              const float* __restrict__ gamma, const float* __restrict__ beta,
                                              int layer, float* __restrict__ sc, float* __restrict__ sh) {
  int c = threadIdx.x;
  if (c >= 64) return;
  float mu = bns[c] * (1.0f / NN);
  float var = bnq[c] * (1.0f / NN) - mu * mu;
  float r = rsqrtf(var + 1e-5f);
  float s = gamma[layer * 64 + c] * r;
  sc[c] = s;
  sh[c] = beta[layer * 64 + c] - mu * s;
}

__global__ __launch_bounds__(256) void k_apply(const float* __restrict__ h2, const float* __restrict__ sc,
                                               const float* __restrict__ sh, float* __restrict__ xbuf) {
  int i = blockIdx.x * 256 + threadIdx.x;   // over NN*16 float4s
  if (i >= NN * 16) return;
  int c4 = i & 15;
  float4 v = ((const float4*)h2)[i];
  float4 s = ((const float4*)sc)[c4], b = ((const float4*)sh)[c4];
  v.x = fmaxf(fmaf(v.x, s.x, b.x), 0.f);
  v.y = fmaxf(fmaf(v.y, s.y, b.y), 0.f);
  v.z = fmaxf(fmaf(v.z, s.z, b.z), 0.f);
  v.w = fmaxf(fmaf(v.w, s.w, b.w), 0.f);
  ((float4*)xbuf)[i] = v;
}

__global__ __launch_bounds__(256) void k_pool(const float* __restrict__ h2, const float* __restrict__ sc,
                                              const float* __restrict__ sh, const int* __restrict__ batch,
                                              float* __restrict__ pooled, int* __restrict__ cnt) {
  int gt = blockIdx.x * 256 + threadIdx.x;
  int node = gt >> 6;
  if (node >= NN) return;
  int c = threadIdx.x & 63;
  float v = fmaxf(fmaf(h2[(size_t)node * 64 + c], sc[c], sh[c]), 0.f);
  int g = batch[node];
  atomicAdd(&pooled[g * 64 + c], v);
  if (c == 0) atomicAdd(&cnt[g], 1);
}

__global__ __launch_bounds__(128) void k_head(const float* __restrict__ pooled, const int* __restrict__ cnt,
                                              const float* __restrict__ hw1, const float* __restrict__ hb1,
                                              const float* __restrict__ hw2, const float* __restrict__ hb2,
                                              float* __restrict__ out) {
  __shared__ float p[64];
  __shared__ float z[128];
  int g = blockIdx.x, t = threadIdx.x;
  if (t < 64) {
    int c = cnt[g];
    float inv = 1.0f / (float)(c > 0 ? c : 1);
    p[t] = pooled[g * 64 + t] * inv;
  }
  __syncthreads();
  float a = hb1[t];
  #pragma unroll
  for (int k = 0; k < 64; k++) a = fmaf(hw1[t * 64 + k], p[k], a);
  z[t] = fmaxf(a, 0.f);
  __syncthreads();
  if (t < OUTC) {
    float b = hb2[t];
    #pragma unroll
    for (int k = 0; k < 128; k++) b = fmaf(hw2[t * 128 + k], z[k], b);
    out[g * OUTC + t] = b;
  }
}

extern "C" void kernel_launch(void* const* d_in, const int* in_sizes, int n_in,
                              void* d_out, int out_size, void* d_ws, size_t ws_size,
                              hipStream_t stream) {
  const float* x_f   = (const float*)d_in[0];
  const int*   ei    = (const int*)d_in[1];
  const float* eattr = (const float*)d_in[2];
  const int*   batch = (const int*)d_in[3];
  const float* l0_ew = (const float*)d_in[4];
  const float* l0_eb = (const float*)d_in[5];
  const float* l0_w1 = (const float*)d_in[6];
  const float* l0_b1 = (const float*)d_in[7];
  const float* l0_w2 = (const float*)d_in[8];
  const float* l0_b2 = (const float*)d_in[9];
  const float* ew    = (const float*)d_in[10];
  const float* eb    = (const float*)d_in[11];
  const float* w1    = (const float*)d_in[12];
  const float* b1    = (const float*)d_in[13];
  const float* w2    = (const float*)d_in[14];
  const float* b2    = (const float*)d_in[15];
  const float* bng   = (const float*)d_in[16];
  const float* bnb   = (const float*)d_in[17];
  const float* hw1   = (const float*)d_in[18];
  const float* hb1   = (const float*)d_in[19];
  const float* hw2   = (const float*)d_in[20];
  const float* hb2   = (const float*)d_in[21];
  const int* esrc = ei;
  const int* edst = ei + NE;

  char* wsb = (char*)d_ws;
  size_t off = 0;
  auto A = [&](size_t bytes) -> void* {
    void* p = wsb + off;
    off = (off + bytes + 255) & ~(size_t)255;
    return p;
  };
  int2*  csr  = (int2*)A((size_t)NE * 8);
  int*   offs = (int*)A((size_t)NN * 4);
  int*   deg  = (int*)A((size_t)NN * 4);
  int*   cur  = (int*)A((size_t)NN * 4);
  int*   bsum = (int*)A(128 * 4);
  float* xbuf = (float*)A((size_t)NN * 64 * 4);
  float* hpre = (float*)A((size_t)NN * 64 * 4);
  float* h2   = (float*)A((size_t)NN * 64 * 4);
  float* bns  = (float*)A(128 * 4);      // bns[64] + bnq[64]
  float* bnq  = bns + 64;
  float* sc   = (float*)A(128 * 4);      // sc[64] + sh[64]
  float* sh   = sc + 64;
  float* pooled = (float*)A((size_t)NG * 64 * 4 + NG * 4);
  int*   cnt  = (int*)(pooled + NG * 64);
  float* w2t  = (float*)A(4 * 4096 * 4); // [4][64][64] transposed

  // zero accumulators
  hipMemsetAsync(deg, 0, (size_t)NN * 4, stream);
  hipMemsetAsync(pooled, 0, (size_t)NG * 64 * 4 + NG * 4, stream);

  // w2 transpose
  k_tr<<<64, 256, 0, stream>>>(l0_w2, w2, w2t);

  // CSR by dst
  k_deg<<<(NE + 255) / 256, 256, 0, stream>>>(edst, deg);
  k_scan1<<<98, 1024, 0, stream>>>(deg, offs, bsum);
  k_scan2<<<1, 128, 0, stream>>>(bsum, 98);
  k_scan3<<<(NN + 255) / 256, 256, 0, stream>>>(offs, bsum, cur);
  k_fill<<<(NE + 255) / 256, 256, 0, stream>>>(esrc, edst, cur, csr);

  const int nodeBlocks = (NN * 64 + 255) / 256;

  // ---- layer 0 (C_in = 32) ----
  k_edge<32><<<nodeBlocks, 256, 0, stream>>>(csr, offs, deg, x_f, eattr, l0_ew, l0_eb, hpre);
  k_mlp<32><<<(NN + 255) / 256, 256, 0, stream>>>(hpre, l0_w1, l0_b1, w2t, l0_b2, h2);
  hipMemsetAsync(bns, 0, 128 * 4, stream);
  k_stats<<<256, 256, 0, stream>>>(h2, bns, bnq);
  k_bnfin<<<1, 64, 0, stream>>>(bns, bnq, bng, bnb, 0, sc, sh);
  k_apply<<<(NN * 16 + 255) / 256, 256, 0, stream>>>(h2, sc, sh, xbuf);

  // ---- layers 1..3 (C_in = 64) ----
  for (int i = 0; i < 3; i++) {
    k_edge<64><<<nodeBlocks, 256, 0, stream>>>(csr, offs, deg, xbuf, eattr,
                                               ew + (size_t)i * 1024, eb + (size_t)i * 64, hpre);
    k_mlp<64><<<(NN + 255) / 256, 256, 0, stream>>>(hpre, w1 + (size_t)i * 4096, b1 + (size_t)i * 64,
                                                    w2t + (size_t)(i + 1) * 4096, b2 + (size_t)i * 64, h2);
    hipMemsetAsync(bns, 0, 128 * 4, stream);
    k_stats<<<256, 256, 0, stream>>>(h2, bns, bnq);
    k_bnfin<<<1, 64, 0, stream>>>(bns, bnq, bng, bnb, i + 1, sc, sh);
    if (i < 2)
      k_apply<<<(NN * 16 + 255) / 256, 256, 0, stream>>>(h2, sc, sh, xbuf);
  }

  // ---- pool + head ----
  k_pool<<<nodeBlocks, 256, 0, stream>>>(h2, sc, sh, batch, pooled, cnt);
  k_head<<<NG, 128, 0, stream>>>(pooled, cnt, hw1, hb1, hw2, hb2, (float*)d_out);
}

// Round 3
// 1802.661 us; speedup vs baseline: 1.3202x; 1.3202x over previous
//
#include <hip/hip_runtime.h>

// Problem constants
#define NN 100000
#define NE 1600000
#define DIN 32
#define DE 16
#define HC 64
#define NL 4
#define MHC 128
#define OUTC 10
#define NG 128

// ---- CSR build ----
__global__ __launch_bounds__(256) void k_deg(const int* __restrict__ dst, int* __restrict__ deg) {
  int e = blockIdx.x * 256 + threadIdx.x;
  if (e < NE) atomicAdd(&deg[dst[e]], 1);
}

__global__ __launch_bounds__(1024) void k_scan1(const int* __restrict__ deg, int* __restrict__ offs, int* __restrict__ bsum) {
  __shared__ int s[1024];
  int t = threadIdx.x;
  int i = blockIdx.x * 1024 + t;
  int v = (i < NN) ? deg[i] : 0;
  s[t] = v; __syncthreads();
  for (int d = 1; d < 1024; d <<= 1) {
    int x = 0;
    if (t >= d) x = s[t - d];
    __syncthreads();
    if (t >= d) s[t] += x;
    __syncthreads();
  }
  if (i < NN) offs[i] = s[t] - v;      // exclusive within block
  if (t == 1023) bsum[blockIdx.x] = s[t];
}

__global__ __launch_bounds__(128) void k_scan2(int* __restrict__ bsum, int nb) {
  __shared__ int s[128];
  int t = threadIdx.x;
  int v = (t < nb) ? bsum[t] : 0;
  s[t] = v; __syncthreads();
  for (int d = 1; d < 128; d <<= 1) {
    int x = 0;
    if (t >= d) x = s[t - d];
    __syncthreads();
    if (t >= d) s[t] += x;
    __syncthreads();
  }
  if (t < nb) bsum[t] = s[t] - v;      // exclusive
}

__global__ __launch_bounds__(256) void k_scan3(int* __restrict__ offs, const int* __restrict__ bsum, int* __restrict__ cur) {
  int i = blockIdx.x * 256 + threadIdx.x;
  if (i < NN) {
    int o = offs[i] + bsum[i >> 10];
    offs[i] = o;
    cur[i] = o;
  }
}

// fill CSR; optionally permute edge_attr into CSR order so layer passes read it sequentially
__global__ __launch_bounds__(256) void k_fill(const int* __restrict__ src, const int* __restrict__ dst,
                                              int* __restrict__ cur, int* __restrict__ csrc, int* __restrict__ ceid,
                                              const float4* __restrict__ eattr4, float4* __restrict__ eperm4,
                                              int doPerm) {
  int e = blockIdx.x * 256 + threadIdx.x;
  if (e < NE) {
    int d = dst[e];
    int pos = atomicAdd(&cur[d], 1);
    csrc[pos] = src[e];
    ceid[pos] = e;
    if (doPerm) {
      float4 a0 = eattr4[(size_t)e * 4 + 0];
      float4 a1 = eattr4[(size_t)e * 4 + 1];
      float4 a2 = eattr4[(size_t)e * 4 + 2];
      float4 a3 = eattr4[(size_t)e * 4 + 3];
      eperm4[(size_t)pos * 4 + 0] = a0;
      eperm4[(size_t)pos * 4 + 1] = a1;
      eperm4[(size_t)pos * 4 + 2] = a2;
      eperm4[(size_t)pos * 4 + 3] = a3;
    }
  }
}

// ---- graph boundaries (batch is sorted): gstart[g] = first node index with batch >= g ----
__global__ __launch_bounds__(256) void k_gstart(const int* __restrict__ batch, int* __restrict__ gstart) {
  int i = blockIdx.x * 256 + threadIdx.x;
  if (i >= NN) return;
  int b = batch[i];
  int bp = (i == 0) ? -1 : batch[i - 1];
  for (int g = bp + 1; g <= b; g++) gstart[g] = i;
  if (i == NN - 1)
    for (int g = b + 1; g <= NG; g++) gstart[g] = NN;
}

// ---- w2 transpose: w2t[mat][c1][c2] = w2[mat][c2][c1] ----
__global__ __launch_bounds__(256) void k_tr(const float* __restrict__ l0w2, const float* __restrict__ w2,
                                            float* __restrict__ w2t) {
  int id = blockIdx.x * 256 + threadIdx.x;   // 4 * 4096
  int mat = id >> 12;
  int j = id & 4095;
  int c1 = j >> 6, c2 = j & 63;
  const float* s = (mat == 0) ? l0w2 : (w2 + (size_t)(mat - 1) * 4096);
  w2t[mat * 4096 + j] = s[c2 * 64 + c1];
}

// ---- edge aggregation: one wave per node, lane = channel, 4-edge unroll for MLP ----
template<int C, bool PERM>
__global__ __launch_bounds__(256) void k_edge(
    const int* __restrict__ csrc, const int* __restrict__ ceid,
    const int* __restrict__ offs, const int* __restrict__ deg,
    const float* __restrict__ xsrc, const float* __restrict__ eattr,
    const float* __restrict__ ewf, const float* __restrict__ ebf,
    float* __restrict__ hpre)
{
  int gt = blockIdx.x * 256 + threadIdx.x;
  int node = gt >> 6;
  if (node >= NN) return;
  int lane = threadIdx.x & 63;
  constexpr int EP = 64 / C;
  int ep = (EP == 1) ? 0 : (lane / C);
  int c = lane % C;
  float w[16];
  const float4* wv = (const float4*)(ewf + c * 16);
  #pragma unroll
  for (int q = 0; q < 4; q++) {
    float4 t = wv[q];
    w[4*q] = t.x; w[4*q+1] = t.y; w[4*q+2] = t.z; w[4*q+3] = t.w;
  }
  float bc = ebf[c];
  int start = offs[node], n = deg[node];
  float acc = 0.f;
  constexpr int U = 4;
  int i = ep;
  for (; i + (U - 1) * EP < n; i += U * EP) {
    int srcn[U];
    float4 A[U][4];
    float xs[U];
    #pragma unroll
    for (int u = 0; u < U; u++) {
      int idx = start + i + u * EP;
      int col = PERM ? idx : ceid[idx];
      const float4* ea = (const float4*)(eattr + (size_t)col * 16);
      A[u][0] = ea[0]; A[u][1] = ea[1]; A[u][2] = ea[2]; A[u][3] = ea[3];
      srcn[u] = csrc[idx];
    }
    #pragma unroll
    for (int u = 0; u < U; u++)
      xs[u] = xsrc[(size_t)srcn[u] * C + c];
    #pragma unroll
    for (int u = 0; u < U; u++) {
      float el = bc;
      el = fmaf(A[u][0].x, w[0],  el); el = fmaf(A[u][0].y, w[1],  el);
      el = fmaf(A[u][0].z, w[2],  el); el = fmaf(A[u][0].w, w[3],  el);
      el = fmaf(A[u][1].x, w[4],  el); el = fmaf(A[u][1].y, w[5],  el);
      el = fmaf(A[u][1].z, w[6],  el); el = fmaf(A[u][1].w, w[7],  el);
      el = fmaf(A[u][2].x, w[8],  el); el = fmaf(A[u][2].y, w[9],  el);
      el = fmaf(A[u][2].z, w[10], el); el = fmaf(A[u][2].w, w[11], el);
      el = fmaf(A[u][3].x, w[12], el); el = fmaf(A[u][3].y, w[13], el);
      el = fmaf(A[u][3].z, w[14], el); el = fmaf(A[u][3].w, w[15], el);
      acc += fmaxf(xs[u] + el, 0.f);
    }
  }
  for (; i < n; i += EP) {
    int idx = start + i;
    int col = PERM ? idx : ceid[idx];
    const float4* ea = (const float4*)(eattr + (size_t)col * 16);
    float4 a0 = ea[0], a1 = ea[1], a2 = ea[2], a3 = ea[3];
    float el = bc;
    el = fmaf(a0.x, w[0],  el); el = fmaf(a0.y, w[1],  el);
    el = fmaf(a0.z, w[2],  el); el = fmaf(a0.w, w[3],  el);
    el = fmaf(a1.x, w[4],  el); el = fmaf(a1.y, w[5],  el);
    el = fmaf(a1.z, w[6],  el); el = fmaf(a1.w, w[7],  el);
    el = fmaf(a2.x, w[8],  el); el = fmaf(a2.y, w[9],  el);
    el = fmaf(a2.z, w[10], el); el = fmaf(a2.w, w[11], el);
    el = fmaf(a3.x, w[12], el); el = fmaf(a3.y, w[13], el);
    el = fmaf(a3.z, w[14], el); el = fmaf(a3.w, w[15], el);
    float xsv = xsrc[(size_t)csrc[idx] * C + c];
    acc += fmaxf(xsv + el, 0.f);
  }
  if (EP == 2) acc += __shfl_xor(acc, 32);
  if (ep == 0) {
    hpre[(size_t)node * C + c] = xsrc[(size_t)node * C + c] + acc;
  }
}

// ---- fused node MLP: one thread per row, wave-uniform (s_load) weights ----
template<int CIN>
__global__ __launch_bounds__(256) void k_mlp(
    const float* __restrict__ hpre,
    const float* __restrict__ w1f, const float* __restrict__ b1f,
    const float* __restrict__ w2tf, const float* __restrict__ b2v,
    float* __restrict__ h2)
{
  int row = blockIdx.x * 256 + threadIdx.x;
  if (row >= NN) return;
  float hrow[CIN];
  const float4* hp = (const float4*)(hpre + (size_t)row * CIN);
  #pragma unroll
  for (int k = 0; k < CIN / 4; k++) {
    float4 v = hp[k];
    hrow[4*k] = v.x; hrow[4*k+1] = v.y; hrow[4*k+2] = v.z; hrow[4*k+3] = v.w;
  }
  float acc2[64];
  #pragma unroll
  for (int c = 0; c < 64; c++) acc2[c] = b2v[c];
  #pragma unroll 4
  for (int c1 = 0; c1 < 64; c1++) {
    float a = b1f[c1];
    #pragma unroll
    for (int k = 0; k < CIN; k++) a = fmaf(w1f[c1 * CIN + k], hrow[k], a);
    a = fmaxf(a, 0.f);
    #pragma unroll
    for (int c2 = 0; c2 < 64; c2++) acc2[c2] = fmaf(w2tf[c1 * 64 + c2], a, acc2[c2]);
  }
  float4* out = (float4*)(h2 + (size_t)row * 64);
  #pragma unroll
  for (int q = 0; q < 16; q++) {
    float4 v;
    v.x = fmaxf(acc2[4*q], 0.f);
    v.y = fmaxf(acc2[4*q+1], 0.f);
    v.z = fmaxf(acc2[4*q+2], 0.f);
    v.w = fmaxf(acc2[4*q+3], 0.f);
    out[q] = v;
  }
}

// ---- BN stats: coalesced float4 pass over h2 ----
__global__ __launch_bounds__(256) void k_stats(const float* __restrict__ h2,
                                               float* __restrict__ bns, float* __restrict__ bnq) {
  int c4 = threadIdx.x & 15, rg = threadIdx.x >> 4;
  float sx = 0, sy = 0, sz = 0, sw = 0;
  float qx = 0, qy = 0, qz = 0, qw = 0;
  for (int r = blockIdx.x * 16 + rg; r < NN; r += gridDim.x * 16) {
    float4 v = *(const float4*)(h2 + (size_t)r * 64 + c4 * 4);
    sx += v.x; sy += v.y; sz += v.z; sw += v.w;
    qx += v.x * v.x; qy += v.y * v.y; qz += v.z * v.z; qw += v.w * v.w;
  }
  __shared__ float4 ls[256], lq[256];
  ls[threadIdx.x] = make_float4(sx, sy, sz, sw);
  lq[threadIdx.x] = make_float4(qx, qy, qz, qw);
  __syncthreads();
  for (int d = 128; d >= 16; d >>= 1) {
    if ((int)threadIdx.x < d) {
      float4 a = ls[threadIdx.x], b = ls[threadIdx.x + d];
      ls[threadIdx.x] = make_float4(a.x + b.x, a.y + b.y, a.z + b.z, a.w + b.w);
      float4 c = lq[threadIdx.x], e = lq[threadIdx.x + d];
      lq[threadIdx.x] = make_float4(c.x + e.x, c.y + e.y, c.z + e.z, c.w + e.w);
    }
    __syncthreads();
  }
  if (threadIdx.x < 16) {
    float4 S = ls[threadIdx.x], Q = lq[threadIdx.x];
    int cb = threadIdx.x * 4;
    atomicAdd(&bns[cb], S.x);   atomicAdd(&bns[cb+1], S.y);
    atomicAdd(&bns[cb+2], S.z); atomicAdd(&bns[cb+3], S.w);
    atomicAdd(&bnq[cb], Q.x);   atomicAdd(&bnq[cb+1], Q.y);
    atomicAdd(&bnq[cb+2], Q.z); atomicAdd(&bnq[cb+3], Q.w);
  }
}

__global__ __launch_bounds__(64) void k_bnfin(const float* __restrict__ bns, const float* __restrict__ bnq,
                                              const float* __restrict__ gamma, const float* __restrict__ beta,
                                              int layer, float* __restrict__ sc, float* __restrict__ sh) {
  int c = threadIdx.x;
  if (c >= 64) return;
  float mu = bns[c] * (1.0f / NN);
  float var = bnq[c] * (1.0f / NN) - mu * mu;
  float r = rsqrtf(var + 1e-5f);
  float s = gamma[layer * 64 + c] * r;
  sc[c] = s;
  sh[c] = beta[layer * 64 + c] - mu * s;
}

__global__ __launch_bounds__(256) void k_apply(const float* __restrict__ h2, const float* __restrict__ sc,
                                               const float* __restrict__ sh, float* __restrict__ xbuf) {
  int i = blockIdx.x * 256 + threadIdx.x;   // over NN*16 float4s
  if (i >= NN * 16) return;
  int c4 = i & 15;
  float4 v = ((const float4*)h2)[i];
  float4 s = ((const float4*)sc)[c4], b = ((const float4*)sh)[c4];
  v.x = fmaxf(fmaf(v.x, s.x, b.x), 0.f);
  v.y = fmaxf(fmaf(v.y, s.y, b.y), 0.f);
  v.z = fmaxf(fmaf(v.z, s.z, b.z), 0.f);
  v.w = fmaxf(fmaf(v.w, s.w, b.w), 0.f);
  ((float4*)xbuf)[i] = v;
}

// ---- pool: one block per (graph, quarter); batch sorted -> contiguous node ranges ----
__global__ __launch_bounds__(256) void k_pool2(const float* __restrict__ h2, const float* __restrict__ sc,
                                               const float* __restrict__ sh, const int* __restrict__ gstart,
                                               float* __restrict__ pooled) {
  int g = blockIdx.x >> 2, sub = blockIdx.x & 3;
  int s = gstart[g], e = gstart[g + 1];
  int c = threadIdx.x & 63, rg = threadIdx.x >> 6;   // 4 row-groups of 64 ch
  float scv = sc[c], shv = sh[c];
  float acc = 0.f;
  for (int r = s + sub * 4 + rg; r < e; r += 16)
    acc += fmaxf(fmaf(h2[(size_t)r * 64 + c], scv, shv), 0.f);
  __shared__ float ls[256];
  ls[threadIdx.x] = acc;
  __syncthreads();
  if (rg == 0) {
    float v = ls[c] + ls[64 + c] + ls[128 + c] + ls[192 + c];
    atomicAdd(&pooled[g * 64 + c], v);
  }
}

__global__ __launch_bounds__(128) void k_head(const float* __restrict__ pooled, const int* __restrict__ gstart,
                                              const float* __restrict__ hw1, const float* __restrict__ hb1,
                                              const float* __restrict__ hw2, const float* __restrict__ hb2,
                                              float* __restrict__ out) {
  __shared__ float p[64];
  __shared__ float z[128];
  int g = blockIdx.x, t = threadIdx.x;
  if (t < 64) {
    int cn = gstart[g + 1] - gstart[g];
    float inv = 1.0f / (float)(cn > 0 ? cn : 1);
    p[t] = pooled[g * 64 + t] * inv;
  }
  __syncthreads();
  float a = hb1[t];
  #pragma unroll
  for (int k = 0; k < 64; k++) a = fmaf(hw1[t * 64 + k], p[k], a);
  z[t] = fmaxf(a, 0.f);
  __syncthreads();
  if (t < OUTC) {
    float b = hb2[t];
    #pragma unroll
    for (int k = 0; k < 128; k++) b = fmaf(hw2[t * 128 + k], z[k], b);
    out[g * OUTC + t] = b;
  }
}

extern "C" void kernel_launch(void* const* d_in, const int* in_sizes, int n_in,
                              void* d_out, int out_size, void* d_ws, size_t ws_size,
                              hipStream_t stream) {
  const float* x_f   = (const float*)d_in[0];
  const int*   ei    = (const int*)d_in[1];
  const float* eattr = (const float*)d_in[2];
  const int*   batch = (const int*)d_in[3];
  const float* l0_ew = (const float*)d_in[4];
  const float* l0_eb = (const float*)d_in[5];
  const float* l0_w1 = (const float*)d_in[6];
  const float* l0_b1 = (const float*)d_in[7];
  const float* l0_w2 = (const float*)d_in[8];
  const float* l0_b2 = (const float*)d_in[9];
  const float* ew    = (const float*)d_in[10];
  const float* eb    = (const float*)d_in[11];
  const float* w1    = (const float*)d_in[12];
  const float* b1    = (const float*)d_in[13];
  const float* w2    = (const float*)d_in[14];
  const float* b2    = (const float*)d_in[15];
  const float* bng   = (const float*)d_in[16];
  const float* bnb   = (const float*)d_in[17];
  const float* hw1   = (const float*)d_in[18];
  const float* hb1   = (const float*)d_in[19];
  const float* hw2   = (const float*)d_in[20];
  const float* hb2   = (const float*)d_in[21];
  const int* esrc = ei;
  const int* edst = ei + NE;

  char* wsb = (char*)d_ws;
  size_t off = 0;
  auto A = [&](size_t bytes) -> void* {
    void* p = wsb + off;
    off = (off + bytes + 255) & ~(size_t)255;
    return p;
  };
  int*   csrc = (int*)A((size_t)NE * 4);
  int*   ceid = (int*)A((size_t)NE * 4);
  int*   offs = (int*)A((size_t)NN * 4);
  int*   deg  = (int*)A((size_t)NN * 4);
  int*   cur  = (int*)A((size_t)NN * 4);
  int*   bsum = (int*)A(128 * 4);
  int*   gst  = (int*)A((NG + 1) * 4);
  float* xbuf = (float*)A((size_t)NN * 64 * 4);
  float* hpre = (float*)A((size_t)NN * 64 * 4);
  float* h2   = (float*)A((size_t)NN * 64 * 4);
  float* bns  = (float*)A(128 * 4);      // bns[64] + bnq[64]
  float* bnq  = bns + 64;
  float* sc   = (float*)A(128 * 4);      // sc[64] + sh[64]
  float* sh   = sc + 64;
  float* pooled = (float*)A((size_t)NG * 64 * 4);
  float* w2t  = (float*)A(4 * 4096 * 4); // [4][64][64] transposed
  size_t baseOff = off;
  float* eperm = (float*)A((size_t)NE * 16 * 4);  // 102.4 MB, optional
  const int doPerm = (ws_size >= off) ? 1 : 0;    // stable across calls -> graph-safe

  // zero accumulators
  hipMemsetAsync(deg, 0, (size_t)NN * 4, stream);
  hipMemsetAsync(pooled, 0, (size_t)NG * 64 * 4, stream);
  (void)baseOff;

  // w2 transpose + graph boundaries
  k_tr<<<64, 256, 0, stream>>>(l0_w2, w2, w2t);
  k_gstart<<<(NN + 255) / 256, 256, 0, stream>>>(batch, gst);

  // CSR by dst
  k_deg<<<(NE + 255) / 256, 256, 0, stream>>>(edst, deg);
  k_scan1<<<98, 1024, 0, stream>>>(deg, offs, bsum);
  k_scan2<<<1, 128, 0, stream>>>(bsum, 98);
  k_scan3<<<(NN + 255) / 256, 256, 0, stream>>>(offs, bsum, cur);
  k_fill<<<(NE + 255) / 256, 256, 0, stream>>>(esrc, edst, cur, csrc, ceid,
                                               (const float4*)eattr, (float4*)eperm, doPerm);

  const int nodeBlocks = (NN * 64 + 255) / 256;
  const float* eatt_use = doPerm ? eperm : eattr;

  // ---- layer 0 (C_in = 32) ----
  if (doPerm)
    k_edge<32, true><<<nodeBlocks, 256, 0, stream>>>(csrc, ceid, offs, deg, x_f, eatt_use, l0_ew, l0_eb, hpre);
  else
    k_edge<32, false><<<nodeBlocks, 256, 0, stream>>>(csrc, ceid, offs, deg, x_f, eatt_use, l0_ew, l0_eb, hpre);
  k_mlp<32><<<(NN + 255) / 256, 256, 0, stream>>>(hpre, l0_w1, l0_b1, w2t, l0_b2, h2);
  hipMemsetAsync(bns, 0, 128 * 4, stream);
  k_stats<<<256, 256, 0, stream>>>(h2, bns, bnq);
  k_bnfin<<<1, 64, 0, stream>>>(bns, bnq, bng, bnb, 0, sc, sh);
  k_apply<<<(NN * 16 + 255) / 256, 256, 0, stream>>>(h2, sc, sh, xbuf);

  // ---- layers 1..3 (C_in = 64) ----
  for (int i = 0; i < 3; i++) {
    if (doPerm)
      k_edge<64, true><<<nodeBlocks, 256, 0, stream>>>(csrc, ceid, offs, deg, xbuf, eatt_use,
                                                       ew + (size_t)i * 1024, eb + (size_t)i * 64, hpre);
    else
      k_edge<64, false><<<nodeBlocks, 256, 0, stream>>>(csrc, ceid, offs, deg, xbuf, eatt_use,
                                                        ew + (size_t)i * 1024, eb + (size_t)i * 64, hpre);
    k_mlp<64><<<(NN + 255) / 256, 256, 0, stream>>>(hpre, w1 + (size_t)i * 4096, b1 + (size_t)i * 64,
                                                    w2t + (size_t)(i + 1) * 4096, b2 + (size_t)i * 64, h2);
    hipMemsetAsync(bns, 0, 128 * 4, stream);
    k_stats<<<256, 256, 0, stream>>>(h2, bns, bnq);
    k_bnfin<<<1, 64, 0, stream>>>(bns, bnq, bng, bnb, i + 1, sc, sh);
    if (i < 2)
      k_apply<<<(NN * 16 + 255) / 256, 256, 0, stream>>>(h2, sc, sh, xbuf);
  }

  // ---- pool + head ----
  k_pool2<<<NG * 4, 256, 0, stream>>>(h2, sc, sh, gst, pooled);
  k_head<<<NG, 128, 0, stream>>>(pooled, gst, hw1, hb1, hw2, hb2, (float*)d_out);
}

// Round 4
// 1661.183 us; speedup vs baseline: 1.4326x; 1.0852x over previous
//
#include <hip/hip_runtime.h>

// Problem constants
#define NN 100000
#define NE 1600000
#define DIN 32
#define DE 16
#define HC 64
#define NL 4
#define MHC 128
#define OUTC 10
#define NG 128

__device__ __forceinline__ const float* uniform_ptr(const float* p) {
  unsigned long long v = (unsigned long long)p;
  unsigned lo = __builtin_amdgcn_readfirstlane((unsigned)v);
  unsigned hi = __builtin_amdgcn_readfirstlane((unsigned)(v >> 32));
  return (const float*)((((unsigned long long)hi) << 32) | lo);
}

// ---- CSR build ----
__global__ __launch_bounds__(256) void k_deg(const int* __restrict__ dst, int* __restrict__ deg) {
  int e = blockIdx.x * 256 + threadIdx.x;
  if (e < NE) atomicAdd(&deg[dst[e]], 1);
}

__global__ __launch_bounds__(1024) void k_scan1(const int* __restrict__ deg, int* __restrict__ offs, int* __restrict__ bsum) {
  __shared__ int s[1024];
  int t = threadIdx.x;
  int i = blockIdx.x * 1024 + t;
  int v = (i < NN) ? deg[i] : 0;
  s[t] = v; __syncthreads();
  for (int d = 1; d < 1024; d <<= 1) {
    int x = 0;
    if (t >= d) x = s[t - d];
    __syncthreads();
    if (t >= d) s[t] += x;
    __syncthreads();
  }
  if (i < NN) offs[i] = s[t] - v;
  if (t == 1023) bsum[blockIdx.x] = s[t];
}

__global__ __launch_bounds__(128) void k_scan2(int* __restrict__ bsum, int nb) {
  __shared__ int s[128];
  int t = threadIdx.x;
  int v = (t < nb) ? bsum[t] : 0;
  s[t] = v; __syncthreads();
  for (int d = 1; d < 128; d <<= 1) {
    int x = 0;
    if (t >= d) x = s[t - d];
    __syncthreads();
    if (t >= d) s[t] += x;
    __syncthreads();
  }
  if (t < nb) bsum[t] = s[t] - v;
}

__global__ __launch_bounds__(256) void k_scan3(int* __restrict__ offs, const int* __restrict__ bsum, int* __restrict__ cur) {
  int i = blockIdx.x * 256 + threadIdx.x;
  if (i < NN) {
    int o = offs[i] + bsum[i >> 10];
    offs[i] = o;
    cur[i] = o;
  }
}

__global__ __launch_bounds__(256) void k_fill(const int* __restrict__ src, const int* __restrict__ dst,
                                              int* __restrict__ cur, int* __restrict__ csrc, int* __restrict__ ceid,
                                              const float4* __restrict__ eattr4, float4* __restrict__ eperm4,
                                              int doPerm) {
  int e = blockIdx.x * 256 + threadIdx.x;
  if (e < NE) {
    int d = dst[e];
    int pos = atomicAdd(&cur[d], 1);
    csrc[pos] = src[e];
    ceid[pos] = e;
    if (doPerm) {
      float4 a0 = eattr4[(size_t)e * 4 + 0];
      float4 a1 = eattr4[(size_t)e * 4 + 1];
      float4 a2 = eattr4[(size_t)e * 4 + 2];
      float4 a3 = eattr4[(size_t)e * 4 + 3];
      eperm4[(size_t)pos * 4 + 0] = a0;
      eperm4[(size_t)pos * 4 + 1] = a1;
      eperm4[(size_t)pos * 4 + 2] = a2;
      eperm4[(size_t)pos * 4 + 3] = a3;
    }
  }
}

// ---- graph boundaries (batch sorted) ----
__global__ __launch_bounds__(256) void k_gstart(const int* __restrict__ batch, int* __restrict__ gstart) {
  int i = blockIdx.x * 256 + threadIdx.x;
  if (i >= NN) return;
  int b = batch[i];
  int bp = (i == 0) ? -1 : batch[i - 1];
  for (int g = bp + 1; g <= b; g++) gstart[g] = i;
  if (i == NN - 1)
    for (int g = b + 1; g <= NG; g++) gstart[g] = NN;
}

// ---- w2 transpose ----
__global__ __launch_bounds__(256) void k_tr(const float* __restrict__ l0w2, const float* __restrict__ w2,
                                            float* __restrict__ w2t) {
  int id = blockIdx.x * 256 + threadIdx.x;
  int mat = id >> 12;
  int j = id & 4095;
  int c1 = j >> 6, c2 = j & 63;
  const float* s = (mat == 0) ? l0w2 : (w2 + (size_t)(mat - 1) * 4096);
  w2t[mat * 4096 + j] = s[c2 * 64 + c1];
}

#define EDGE_DOT(el, a0, a1, a2, a3)                              \
  el = fmaf(a0.x, w[0],  el); el = fmaf(a0.y, w[1],  el);         \
  el = fmaf(a0.z, w[2],  el); el = fmaf(a0.w, w[3],  el);         \
  el = fmaf(a1.x, w[4],  el); el = fmaf(a1.y, w[5],  el);         \
  el = fmaf(a1.z, w[6],  el); el = fmaf(a1.w, w[7],  el);         \
  el = fmaf(a2.x, w[8],  el); el = fmaf(a2.y, w[9],  el);         \
  el = fmaf(a2.z, w[10], el); el = fmaf(a2.w, w[11], el);         \
  el = fmaf(a3.x, w[12], el); el = fmaf(a3.y, w[13], el);         \
  el = fmaf(a3.z, w[14], el); el = fmaf(a3.w, w[15], el);

// ---- edge aggregation C=64, BN+relu fused on gather; chunked shfl-prefetch ----
template<bool PERM, bool BN>
__global__ __launch_bounds__(256) void k_edge64(
    const int* __restrict__ csrc, const int* __restrict__ ceid,
    const int* __restrict__ offs, const int* __restrict__ deg,
    const float* __restrict__ xsrc, const float* __restrict__ scp, const float* __restrict__ shp,
    const float* __restrict__ eattr,
    const float* __restrict__ ewf, const float* __restrict__ ebf,
    float* __restrict__ hpre)
{
  int gt = blockIdx.x * 256 + threadIdx.x;
  int node = gt >> 6;
  if (node >= NN) return;
  int c = threadIdx.x & 63;
  float w[16];
  {
    const float4* wv = (const float4*)(ewf + c * 16);
    float4 t0 = wv[0], t1 = wv[1], t2 = wv[2], t3 = wv[3];
    w[0]=t0.x; w[1]=t0.y; w[2]=t0.z; w[3]=t0.w;
    w[4]=t1.x; w[5]=t1.y; w[6]=t1.z; w[7]=t1.w;
    w[8]=t2.x; w[9]=t2.y; w[10]=t2.z; w[11]=t2.w;
    w[12]=t3.x; w[13]=t3.y; w[14]=t3.z; w[15]=t3.w;
  }
  float bc = ebf[c];
  float scv = 1.f, shv = 0.f;
  if (BN) { scv = scp[c]; shv = shp[c]; }
  int start = offs[node], n = deg[node];
  float acc = 0.f;
  for (int base = 0; base < n; base += 64) {
    int cn = min(64, n - base);
    int sidx = (c < cn) ? csrc[start + base + c] : 0;
    for (int b = 0; b < cn; b += 8) {
      float xv[8];
      #pragma unroll
      for (int u = 0; u < 8; u++) {
        int s = __shfl(sidx, b + u);
        xv[u] = xsrc[(size_t)s * 64 + c];
      }
      int ub = cn - b;
      if (PERM) {
        const float* ebase = uniform_ptr(eattr + (size_t)(start + base + b) * 16);
        #pragma unroll
        for (int u = 0; u < 8; u++) {
          if (u >= ub) break;
          const float4* ea = (const float4*)(ebase + u * 16);
          float4 a0 = ea[0], a1 = ea[1], a2 = ea[2], a3 = ea[3];
          float el = bc;
          EDGE_DOT(el, a0, a1, a2, a3);
          float xs = xv[u];
          if (BN) xs = fmaxf(fmaf(xs, scv, shv), 0.f);
          acc += fmaxf(xs + el, 0.f);
        }
      } else {
        #pragma unroll
        for (int u = 0; u < 8; u++) {
          if (u >= ub) break;
          size_t epos = (size_t)ceid[start + base + b + u];
          const float4* ea = (const float4*)uniform_ptr(eattr + epos * 16);
          float4 a0 = ea[0], a1 = ea[1], a2 = ea[2], a3 = ea[3];
          float el = bc;
          EDGE_DOT(el, a0, a1, a2, a3);
          float xs = xv[u];
          if (BN) xs = fmaxf(fmaf(xs, scv, shv), 0.f);
          acc += fmaxf(xs + el, 0.f);
        }
      }
    }
  }
  float xself = xsrc[(size_t)node * 64 + c];
  if (BN) xself = fmaxf(fmaf(xself, scv, shv), 0.f);
  hpre[(size_t)node * 64 + c] = xself + acc;
}

// ---- edge aggregation C=32 (layer 0, raw x): 2 edge-groups x 32 channels ----
template<bool PERM>
__global__ __launch_bounds__(256) void k_edge32(
    const int* __restrict__ csrc, const int* __restrict__ ceid,
    const int* __restrict__ offs, const int* __restrict__ deg,
    const float* __restrict__ xsrc, const float* __restrict__ eattr,
    const float* __restrict__ ewf, const float* __restrict__ ebf,
    float* __restrict__ hpre)
{
  int gt = blockIdx.x * 256 + threadIdx.x;
  int node = gt >> 6;
  if (node >= NN) return;
  int lane = threadIdx.x & 63;
  int ep = lane >> 5;
  int c = lane & 31;
  float w[16];
  {
    const float4* wv = (const float4*)(ewf + c * 16);
    float4 t0 = wv[0], t1 = wv[1], t2 = wv[2], t3 = wv[3];
    w[0]=t0.x; w[1]=t0.y; w[2]=t0.z; w[3]=t0.w;
    w[4]=t1.x; w[5]=t1.y; w[6]=t1.z; w[7]=t1.w;
    w[8]=t2.x; w[9]=t2.y; w[10]=t2.z; w[11]=t2.w;
    w[12]=t3.x; w[13]=t3.y; w[14]=t3.z; w[15]=t3.w;
  }
  float bc = ebf[c];
  int start = offs[node], n = deg[node];
  float acc = 0.f;
  for (int base = 0; base < n; base += 64) {
    int cn = min(64, n - base);
    int sidx = (lane < cn) ? csrc[start + base + lane] : 0;
    for (int b = 0; b < cn; b += 16) {
      float xv[8];
      #pragma unroll
      for (int u = 0; u < 8; u++) {
        int ei = (b + 2 * u + ep) & 63;
        int s = __shfl(sidx, ei);
        xv[u] = xsrc[(size_t)s * 32 + c];
      }
      int ub = cn - b;
      #pragma unroll
      for (int u = 0; u < 8; u++) {
        int myi = 2 * u + ep;
        if (myi >= ub) break;
        size_t epos = PERM ? (size_t)(start + base + b + myi) : (size_t)ceid[start + base + b + myi];
        const float4* ea = (const float4*)(eattr + epos * 16);
        float4 a0 = ea[0], a1 = ea[1], a2 = ea[2], a3 = ea[3];
        float el = bc;
        EDGE_DOT(el, a0, a1, a2, a3);
        acc += fmaxf(xv[u] + el, 0.f);
      }
    }
  }
  acc += __shfl_xor(acc, 32);
  if (ep == 0)
    hpre[(size_t)node * 32 + c] = xsrc[(size_t)node * 32 + c] + acc;
}

// ---- fused node MLP + BN-stats epilogue ----
template<int CIN>
__global__ __launch_bounds__(256) void k_mlp(
    const float* __restrict__ hpre,
    const float* __restrict__ w1f, const float* __restrict__ b1f,
    const float* __restrict__ w2tf, const float* __restrict__ b2v,
    float* __restrict__ h2, float* __restrict__ bnsq)
{
  int row0 = blockIdx.x * 256 + threadIdx.x;
  bool act = row0 < NN;
  int row = act ? row0 : (NN - 1);
  float hrow[CIN];
  const float4* hp = (const float4*)(hpre + (size_t)row * CIN);
  #pragma unroll
  for (int k = 0; k < CIN / 4; k++) {
    float4 v = hp[k];
    hrow[4*k] = v.x; hrow[4*k+1] = v.y; hrow[4*k+2] = v.z; hrow[4*k+3] = v.w;
  }
  float acc2[64];
  #pragma unroll
  for (int c = 0; c < 64; c++) acc2[c] = b2v[c];
  #pragma unroll 4
  for (int c1 = 0; c1 < 64; c1++) {
    float a = b1f[c1];
    #pragma unroll
    for (int k = 0; k < CIN; k++) a = fmaf(w1f[c1 * CIN + k], hrow[k], a);
    a = fmaxf(a, 0.f);
    #pragma unroll
    for (int c2 = 0; c2 < 64; c2++) acc2[c2] = fmaf(w2tf[c1 * 64 + c2], a, acc2[c2]);
  }
  #pragma unroll
  for (int c = 0; c < 64; c++) acc2[c] = fmaxf(acc2[c], 0.f);
  if (act) {
    float4* out = (float4*)(h2 + (size_t)row * 64);
    #pragma unroll
    for (int q = 0; q < 16; q++)
      out[q] = make_float4(acc2[4*q], acc2[4*q+1], acc2[4*q+2], acc2[4*q+3]);
  } else {
    #pragma unroll
    for (int c = 0; c < 64; c++) acc2[c] = 0.f;
  }
  // BN stats: wave butterfly -> LDS -> global atomics
  __shared__ float part[4][128];
  int wid = threadIdx.x >> 6, lane = threadIdx.x & 63;
  #pragma unroll
  for (int c = 0; c < 64; c++) {
    float s = acc2[c], q = s * s;
    #pragma unroll
    for (int m = 1; m < 64; m <<= 1) { s += __shfl_xor(s, m); q += __shfl_xor(q, m); }
    if (lane == 0) { part[wid][c] = s; part[wid][64 + c] = q; }
  }
  __syncthreads();
  if (threadIdx.x < 128) {
    float v = part[0][threadIdx.x] + part[1][threadIdx.x] + part[2][threadIdx.x] + part[3][threadIdx.x];
    atomicAdd(&bnsq[threadIdx.x], v);
  }
}

__global__ __launch_bounds__(64) void k_bnfin(const float* __restrict__ bnsq,
                                              const float* __restrict__ gamma, const float* __restrict__ beta,
                                              int layer, float* __restrict__ scs, float* __restrict__ shs) {
  int c = threadIdx.x;
  if (c >= 64) return;
  const float* sl = bnsq + layer * 128;
  float mu = sl[c] * (1.0f / NN);
  float var = sl[64 + c] * (1.0f / NN) - mu * mu;
  float r = rsqrtf(var + 1e-5f);
  float s = gamma[layer * 64 + c] * r;
  scs[layer * 64 + c] = s;
  shs[layer * 64 + c] = beta[layer * 64 + c] - mu * s;
}

// ---- pool: BN+relu on the fly; batch sorted -> contiguous ranges ----
__global__ __launch_bounds__(256) void k_pool2(const float* __restrict__ h2, const float* __restrict__ sc,
                                               const float* __restrict__ sh, const int* __restrict__ gstart,
                                               float* __restrict__ pooled) {
  int g = blockIdx.x >> 2, sub = blockIdx.x & 3;
  int s = gstart[g], e = gstart[g + 1];
  int c = threadIdx.x & 63, rg = threadIdx.x >> 6;
  float scv = sc[c], shv = sh[c];
  float acc = 0.f;
  for (int r = s + sub * 4 + rg; r < e; r += 16)
    acc += fmaxf(fmaf(h2[(size_t)r * 64 + c], scv, shv), 0.f);
  __shared__ float ls[256];
  ls[threadIdx.x] = acc;
  __syncthreads();
  if (rg == 0) {
    float v = ls[c] + ls[64 + c] + ls[128 + c] + ls[192 + c];
    atomicAdd(&pooled[g * 64 + c], v);
  }
}

__global__ __launch_bounds__(128) void k_head(const float* __restrict__ pooled, const int* __restrict__ gstart,
                                              const float* __restrict__ hw1, const float* __restrict__ hb1,
                                              const float* __restrict__ hw2, const float* __restrict__ hb2,
                                              float* __restrict__ out) {
  __shared__ float p[64];
  __shared__ float z[128];
  int g = blockIdx.x, t = threadIdx.x;
  if (t < 64) {
    int cn = gstart[g + 1] - gstart[g];
    float inv = 1.0f / (float)(cn > 0 ? cn : 1);
    p[t] = pooled[g * 64 + t] * inv;
  }
  __syncthreads();
  float a = hb1[t];
  #pragma unroll
  for (int k = 0; k < 64; k++) a = fmaf(hw1[t * 64 + k], p[k], a);
  z[t] = fmaxf(a, 0.f);
  __syncthreads();
  if (t < OUTC) {
    float b = hb2[t];
    #pragma unroll
    for (int k = 0; k < 128; k++) b = fmaf(hw2[t * 128 + k], z[k], b);
    out[g * OUTC + t] = b;
  }
}

extern "C" void kernel_launch(void* const* d_in, const int* in_sizes, int n_in,
                              void* d_out, int out_size, void* d_ws, size_t ws_size,
                              hipStream_t stream) {
  const float* x_f   = (const float*)d_in[0];
  const int*   ei    = (const int*)d_in[1];
  const float* eattr = (const float*)d_in[2];
  const int*   batch = (const int*)d_in[3];
  const float* l0_ew = (const float*)d_in[4];
  const float* l0_eb = (const float*)d_in[5];
  const float* l0_w1 = (const float*)d_in[6];
  const float* l0_b1 = (const float*)d_in[7];
  const float* l0_w2 = (const float*)d_in[8];
  const float* l0_b2 = (const float*)d_in[9];
  const float* ew    = (const float*)d_in[10];
  const float* eb    = (const float*)d_in[11];
  const float* w1    = (const float*)d_in[12];
  const float* b1    = (const float*)d_in[13];
  const float* w2    = (const float*)d_in[14];
  const float* b2    = (const float*)d_in[15];
  const float* bng   = (const float*)d_in[16];
  const float* bnb   = (const float*)d_in[17];
  const float* hw1   = (const float*)d_in[18];
  const float* hb1   = (const float*)d_in[19];
  const float* hw2   = (const float*)d_in[20];
  const float* hb2   = (const float*)d_in[21];
  const int* esrc = ei;
  const int* edst = ei + NE;

  char* wsb = (char*)d_ws;
  size_t off = 0;
  auto A = [&](size_t bytes) -> void* {
    void* p = wsb + off;
    off = (off + bytes + 255) & ~(size_t)255;
    return p;
  };
  int*   csrc = (int*)A((size_t)NE * 4);
  int*   ceid = (int*)A((size_t)NE * 4);
  int*   offs = (int*)A((size_t)NN * 4);
  int*   deg  = (int*)A((size_t)NN * 4);
  int*   cur  = (int*)A((size_t)NN * 4);
  int*   bsum = (int*)A(128 * 4);
  int*   gst  = (int*)A((NG + 1) * 4);
  float* hpre = (float*)A((size_t)NN * 64 * 4);
  float* h2   = (float*)A((size_t)NN * 64 * 4);
  float* bnsq = (float*)A(4 * 128 * 4);   // [layer][sum64|sq64]
  float* scs  = (float*)A(4 * 64 * 4);    // per-layer scale
  float* shs  = (float*)A(4 * 64 * 4);    // per-layer shift
  float* pooled = (float*)A((size_t)NG * 64 * 4);
  float* w2t  = (float*)A(4 * 4096 * 4);
  float* eperm = (float*)A((size_t)NE * 16 * 4);  // 102.4 MB, optional
  const int doPerm = (ws_size >= off) ? 1 : 0;    // stable across calls -> graph-safe

  hipMemsetAsync(deg, 0, (size_t)NN * 4, stream);
  hipMemsetAsync(bnsq, 0, 4 * 128 * 4, stream);
  hipMemsetAsync(pooled, 0, (size_t)NG * 64 * 4, stream);

  k_tr<<<64, 256, 0, stream>>>(l0_w2, w2, w2t);
  k_gstart<<<(NN + 255) / 256, 256, 0, stream>>>(batch, gst);

  k_deg<<<(NE + 255) / 256, 256, 0, stream>>>(edst, deg);
  k_scan1<<<98, 1024, 0, stream>>>(deg, offs, bsum);
  k_scan2<<<1, 128, 0, stream>>>(bsum, 98);
  k_scan3<<<(NN + 255) / 256, 256, 0, stream>>>(offs, bsum, cur);
  k_fill<<<(NE + 255) / 256, 256, 0, stream>>>(esrc, edst, cur, csrc, ceid,
                                               (const float4*)eattr, (float4*)eperm, doPerm);

  const int nodeBlocks = (NN * 64 + 255) / 256;
  const int rowBlocks = (NN + 255) / 256;
  const float* eatt_use = doPerm ? eperm : eattr;

  // ---- layer 0 ----
  if (doPerm)
    k_edge32<true><<<nodeBlocks, 256, 0, stream>>>(csrc, ceid, offs, deg, x_f, eatt_use, l0_ew, l0_eb, hpre);
  else
    k_edge32<false><<<nodeBlocks, 256, 0, stream>>>(csrc, ceid, offs, deg, x_f, eatt_use, l0_ew, l0_eb, hpre);
  k_mlp<32><<<rowBlocks, 256, 0, stream>>>(hpre, l0_w1, l0_b1, w2t, l0_b2, h2, bnsq + 0);
  k_bnfin<<<1, 64, 0, stream>>>(bnsq, bng, bnb, 0, scs, shs);

  // ---- layers 1..3: gather from h2 with fused BN(prev)+relu ----
  for (int i = 0; i < 3; i++) {
    if (doPerm)
      k_edge64<true, true><<<nodeBlocks, 256, 0, stream>>>(csrc, ceid, offs, deg, h2,
                                                           scs + i * 64, shs + i * 64, eatt_use,
                                                           ew + (size_t)i * 1024, eb + (size_t)i * 64, hpre);
    else
      k_edge64<false, true><<<nodeBlocks, 256, 0, stream>>>(csrc, ceid, offs, deg, h2,
                                                            scs + i * 64, shs + i * 64, eatt_use,
                                                            ew + (size_t)i * 1024, eb + (size_t)i * 64, hpre);
    k_mlp<64><<<rowBlocks, 256, 0, stream>>>(hpre, w1 + (size_t)i * 4096, b1 + (size_t)i * 64,
                                             w2t + (size_t)(i + 1) * 4096, b2 + (size_t)i * 64,
                                             h2, bnsq + (i + 1) * 128);
    k_bnfin<<<1, 64, 0, stream>>>(bnsq, bng, bnb, i + 1, scs, shs);
  }

  // ---- pool (applies BN layer 3) + head ----
  k_pool2<<<NG * 4, 256, 0, stream>>>(h2, scs + 3 * 64, shs + 3 * 64, gst, pooled);
  k_head<<<NG, 128, 0, stream>>>(pooled, gst, hw1, hb1, hw2, hb2, (float*)d_out);
}

// Round 5
// 1583.187 us; speedup vs baseline: 1.5032x; 1.0493x over previous
//
#include <hip/hip_runtime.h>

// Problem constants
#define NN 100000
#define NE 1600000
#define DIN 32
#define DE 16
#define HC 64
#define NL 4
#define MHC 128
#define OUTC 10
#define NG 128

// ---- CSR build ----
__global__ __launch_bounds__(256) void k_deg(const int* __restrict__ dst, int* __restrict__ deg) {
  int e = blockIdx.x * 256 + threadIdx.x;
  if (e < NE) atomicAdd(&deg[dst[e]], 1);
}

__global__ __launch_bounds__(1024) void k_scan1(const int* __restrict__ deg, int* __restrict__ offs, int* __restrict__ bsum) {
  __shared__ int s[1024];
  int t = threadIdx.x;
  int i = blockIdx.x * 1024 + t;
  int v = (i < NN) ? deg[i] : 0;
  s[t] = v; __syncthreads();
  for (int d = 1; d < 1024; d <<= 1) {
    int x = 0;
    if (t >= d) x = s[t - d];
    __syncthreads();
    if (t >= d) s[t] += x;
    __syncthreads();
  }
  if (i < NN) offs[i] = s[t] - v;
  if (t == 1023) bsum[blockIdx.x] = s[t];
}

__global__ __launch_bounds__(128) void k_scan2(int* __restrict__ bsum, int nb) {
  __shared__ int s[128];
  int t = threadIdx.x;
  int v = (t < nb) ? bsum[t] : 0;
  s[t] = v; __syncthreads();
  for (int d = 1; d < 128; d <<= 1) {
    int x = 0;
    if (t >= d) x = s[t - d];
    __syncthreads();
    if (t >= d) s[t] += x;
    __syncthreads();
  }
  if (t < nb) bsum[t] = s[t] - v;
}

__global__ __launch_bounds__(256) void k_scan3(int* __restrict__ offs, const int* __restrict__ bsum, int* __restrict__ cur) {
  int i = blockIdx.x * 256 + threadIdx.x;
  if (i < NN) {
    int o = offs[i] + bsum[i >> 10];
    offs[i] = o;
    cur[i] = o;
  }
}

__global__ __launch_bounds__(256) void k_fill(const int* __restrict__ src, const int* __restrict__ dst,
                                              int* __restrict__ cur, int* __restrict__ csrc, int* __restrict__ ceid,
                                              const float4* __restrict__ eattr4, float4* __restrict__ eperm4,
                                              int doPerm) {
  int e = blockIdx.x * 256 + threadIdx.x;
  if (e < NE) {
    int d = dst[e];
    int pos = atomicAdd(&cur[d], 1);
    csrc[pos] = src[e];
    ceid[pos] = e;
    if (doPerm) {
      float4 a0 = eattr4[(size_t)e * 4 + 0];
      float4 a1 = eattr4[(size_t)e * 4 + 1];
      float4 a2 = eattr4[(size_t)e * 4 + 2];
      float4 a3 = eattr4[(size_t)e * 4 + 3];
      eperm4[(size_t)pos * 4 + 0] = a0;
      eperm4[(size_t)pos * 4 + 1] = a1;
      eperm4[(size_t)pos * 4 + 2] = a2;
      eperm4[(size_t)pos * 4 + 3] = a3;
    }
  }
}

// ---- graph boundaries (batch sorted) ----
__global__ __launch_bounds__(256) void k_gstart(const int* __restrict__ batch, int* __restrict__ gstart) {
  int i = blockIdx.x * 256 + threadIdx.x;
  if (i >= NN) return;
  int b = batch[i];
  int bp = (i == 0) ? -1 : batch[i - 1];
  for (int g = bp + 1; g <= b; g++) gstart[g] = i;
  if (i == NN - 1)
    for (int g = b + 1; g <= NG; g++) gstart[g] = NN;
}

// ---- w2 transpose ----
__global__ __launch_bounds__(256) void k_tr(const float* __restrict__ l0w2, const float* __restrict__ w2,
                                            float* __restrict__ w2t) {
  int id = blockIdx.x * 256 + threadIdx.x;
  int mat = id >> 12;
  int j = id & 4095;
  int c1 = j >> 6, c2 = j & 63;
  const float* s = (mat == 0) ? l0w2 : (w2 + (size_t)(mat - 1) * 4096);
  w2t[mat * 4096 + j] = s[c2 * 64 + c1];
}

#define EDGE_DOT(el, a0, a1, a2, a3)                              \
  el = fmaf(a0.x, w[0],  el); el = fmaf(a0.y, w[1],  el);         \
  el = fmaf(a0.z, w[2],  el); el = fmaf(a0.w, w[3],  el);         \
  el = fmaf(a1.x, w[4],  el); el = fmaf(a1.y, w[5],  el);         \
  el = fmaf(a1.z, w[6],  el); el = fmaf(a1.w, w[7],  el);         \
  el = fmaf(a2.x, w[8],  el); el = fmaf(a2.y, w[9],  el);         \
  el = fmaf(a2.z, w[10], el); el = fmaf(a2.w, w[11], el);         \
  el = fmaf(a3.x, w[12], el); el = fmaf(a3.y, w[13], el);         \
  el = fmaf(a3.z, w[14], el); el = fmaf(a3.w, w[15], el);

// ---- edge aggregation: wave per node; 16-edge chunks; eattr via LDS broadcast;
//      16 x-gathers in flight; optional BN+relu fused onto gathered x ----
template<int C, bool BN, bool PERM>
__global__ __launch_bounds__(256) void k_edgeB(
    const int* __restrict__ csrc, const int* __restrict__ ceid,
    const int* __restrict__ offs, const int* __restrict__ deg,
    const float* __restrict__ xsrc, const float* __restrict__ scp, const float* __restrict__ shp,
    const float* __restrict__ eattr,
    const float* __restrict__ ewf, const float* __restrict__ ebf,
    float* __restrict__ hpre)
{
  __shared__ float sm[4][256];     // per-wave 16 edges x 16 floats
  int gt = blockIdx.x * 256 + threadIdx.x;
  int node = gt >> 6;
  if (node >= NN) return;
  int wid = threadIdx.x >> 6;
  int ll = threadIdx.x & 63;
  int ep = (C == 64) ? 0 : (ll >> 5);
  int c = (C == 64) ? ll : (ll & 31);
  float w[16];
  {
    const float4* wv = (const float4*)(ewf + c * 16);
    float4 t0 = wv[0], t1 = wv[1], t2 = wv[2], t3 = wv[3];
    w[0]=t0.x; w[1]=t0.y; w[2]=t0.z; w[3]=t0.w;
    w[4]=t1.x; w[5]=t1.y; w[6]=t1.z; w[7]=t1.w;
    w[8]=t2.x; w[9]=t2.y; w[10]=t2.z; w[11]=t2.w;
    w[12]=t3.x; w[13]=t3.y; w[14]=t3.z; w[15]=t3.w;
  }
  float bc = ebf[c];
  float scv = 1.f, shv = 0.f;
  if (BN) { scv = scp[c]; shv = shp[c]; }
  int start = offs[node], n = deg[node];
  float acc = 0.f;

  for (int base = 0; base < n; base += 16) {
    int cn = min(16, n - base);
    // stage eattr chunk into this wave's LDS slot: lane ll covers edge ll>>2, quarter ll&3
    int q = ll >> 2;
    if (q < cn) {
      int pos = PERM ? (start + base + q) : ceid[start + base + q];
      float4 v = *(const float4*)(eattr + (size_t)pos * 16 + (ll & 3) * 4);
      *(float4*)&sm[wid][ll * 4] = v;
    }
    // src indices for the chunk
    int sidx = 0;
    if (ll < cn) sidx = csrc[start + base + ll];
    __builtin_amdgcn_wave_barrier();

    if (C == 64) {
      float xv[16];
      #pragma unroll
      for (int u = 0; u < 16; u++) {
        if (u < cn) {
          int s = __shfl(sidx, u);
          xv[u] = xsrc[(size_t)s * 64 + c];
        } else xv[u] = 0.f;
      }
      #pragma unroll
      for (int u = 0; u < 16; u++) {
        if (u >= cn) break;
        float4 a0 = *(const float4*)&sm[wid][u * 16 + 0];
        float4 a1 = *(const float4*)&sm[wid][u * 16 + 4];
        float4 a2 = *(const float4*)&sm[wid][u * 16 + 8];
        float4 a3 = *(const float4*)&sm[wid][u * 16 + 12];
        float el = bc;
        EDGE_DOT(el, a0, a1, a2, a3);
        float xs = xv[u];
        if (BN) xs = fmaxf(fmaf(xs, scv, shv), 0.f);
        acc += fmaxf(xs + el, 0.f);
      }
    } else {
      float xv[8];
      #pragma unroll
      for (int j = 0; j < 8; j++) {
        int u = 2 * j + ep;
        int uc = (u < cn) ? u : 0;
        int s = __shfl(sidx, uc);
        xv[j] = xsrc[(size_t)s * 32 + c];
      }
      #pragma unroll
      for (int j = 0; j < 8; j++) {
        if (2 * j >= cn) break;
        int u = 2 * j + ep;
        float4 a0 = *(const float4*)&sm[wid][u * 16 + 0];
        float4 a1 = *(const float4*)&sm[wid][u * 16 + 4];
        float4 a2 = *(const float4*)&sm[wid][u * 16 + 8];
        float4 a3 = *(const float4*)&sm[wid][u * 16 + 12];
        float el = bc;
        EDGE_DOT(el, a0, a1, a2, a3);
        if (u < cn) acc += fmaxf(xv[j] + el, 0.f);
      }
    }
  }

  if (C == 64) {
    float xself = xsrc[(size_t)node * 64 + c];
    if (BN) xself = fmaxf(fmaf(xself, scv, shv), 0.f);
    hpre[(size_t)node * 64 + c] = xself + acc;
  } else {
    acc += __shfl_xor(acc, 32);
    if (ep == 0)
      hpre[(size_t)node * 32 + c] = xsrc[(size_t)node * 32 + c] + acc;
  }
}

// ---- fused node MLP + BN-stats epilogue ----
template<int CIN>
__global__ __launch_bounds__(256) void k_mlp(
    const float* __restrict__ hpre,
    const float* __restrict__ w1f, const float* __restrict__ b1f,
    const float* __restrict__ w2tf, const float* __restrict__ b2v,
    float* __restrict__ h2, float* __restrict__ bnsq)
{
  int row0 = blockIdx.x * 256 + threadIdx.x;
  bool act = row0 < NN;
  int row = act ? row0 : (NN - 1);
  float hrow[CIN];
  const float4* hp = (const float4*)(hpre + (size_t)row * CIN);
  #pragma unroll
  for (int k = 0; k < CIN / 4; k++) {
    float4 v = hp[k];
    hrow[4*k] = v.x; hrow[4*k+1] = v.y; hrow[4*k+2] = v.z; hrow[4*k+3] = v.w;
  }
  float acc2[64];
  #pragma unroll
  for (int c = 0; c < 64; c++) acc2[c] = b2v[c];
  #pragma unroll 4
  for (int c1 = 0; c1 < 64; c1++) {
    float a = b1f[c1];
    #pragma unroll
    for (int k = 0; k < CIN; k++) a = fmaf(w1f[c1 * CIN + k], hrow[k], a);
    a = fmaxf(a, 0.f);
    #pragma unroll
    for (int c2 = 0; c2 < 64; c2++) acc2[c2] = fmaf(w2tf[c1 * 64 + c2], a, acc2[c2]);
  }
  #pragma unroll
  for (int c = 0; c < 64; c++) acc2[c] = fmaxf(acc2[c], 0.f);
  if (act) {
    float4* out = (float4*)(h2 + (size_t)row * 64);
    #pragma unroll
    for (int q = 0; q < 16; q++)
      out[q] = make_float4(acc2[4*q], acc2[4*q+1], acc2[4*q+2], acc2[4*q+3]);
  } else {
    #pragma unroll
    for (int c = 0; c < 64; c++) acc2[c] = 0.f;
  }
  // BN stats: wave butterfly -> LDS -> global atomics
  __shared__ float part[4][128];
  int wid = threadIdx.x >> 6, lane = threadIdx.x & 63;
  #pragma unroll
  for (int c = 0; c < 64; c++) {
    float s = acc2[c], q = s * s;
    #pragma unroll
    for (int m = 1; m < 64; m <<= 1) { s += __shfl_xor(s, m); q += __shfl_xor(q, m); }
    if (lane == 0) { part[wid][c] = s; part[wid][64 + c] = q; }
  }
  __syncthreads();
  if (threadIdx.x < 128) {
    float v = part[0][threadIdx.x] + part[1][threadIdx.x] + part[2][threadIdx.x] + part[3][threadIdx.x];
    atomicAdd(&bnsq[threadIdx.x], v);
  }
}

__global__ __launch_bounds__(64) void k_bnfin(const float* __restrict__ bnsq,
                                              const float* __restrict__ gamma, const float* __restrict__ beta,
                                              int layer, float* __restrict__ scs, float* __restrict__ shs) {
  int c = threadIdx.x;
  if (c >= 64) return;
  const float* sl = bnsq + layer * 128;
  float mu = sl[c] * (1.0f / NN);
  float var = sl[64 + c] * (1.0f / NN) - mu * mu;
  float r = rsqrtf(var + 1e-5f);
  float s = gamma[layer * 64 + c] * r;
  scs[layer * 64 + c] = s;
  shs[layer * 64 + c] = beta[layer * 64 + c] - mu * s;
}

// ---- pool: BN+relu on the fly; batch sorted -> contiguous ranges ----
__global__ __launch_bounds__(256) void k_pool2(const float* __restrict__ h2, const float* __restrict__ sc,
                                               const float* __restrict__ sh, const int* __restrict__ gstart,
                                               float* __restrict__ pooled) {
  int g = blockIdx.x >> 2, sub = blockIdx.x & 3;
  int s = gstart[g], e = gstart[g + 1];
  int c = threadIdx.x & 63, rg = threadIdx.x >> 6;
  float scv = sc[c], shv = sh[c];
  float acc = 0.f;
  for (int r = s + sub * 4 + rg; r < e; r += 16)
    acc += fmaxf(fmaf(h2[(size_t)r * 64 + c], scv, shv), 0.f);
  __shared__ float ls[256];
  ls[threadIdx.x] = acc;
  __syncthreads();
  if (rg == 0) {
    float v = ls[c] + ls[64 + c] + ls[128 + c] + ls[192 + c];
    atomicAdd(&pooled[g * 64 + c], v);
  }
}

__global__ __launch_bounds__(128) void k_head(const float* __restrict__ pooled, const int* __restrict__ gstart,
                                              const float* __restrict__ hw1, const float* __restrict__ hb1,
                                              const float* __restrict__ hw2, const float* __restrict__ hb2,
                                              float* __restrict__ out) {
  __shared__ float p[64];
  __shared__ float z[128];
  int g = blockIdx.x, t = threadIdx.x;
  if (t < 64) {
    int cn = gstart[g + 1] - gstart[g];
    float inv = 1.0f / (float)(cn > 0 ? cn : 1);
    p[t] = pooled[g * 64 + t] * inv;
  }
  __syncthreads();
  float a = hb1[t];
  #pragma unroll
  for (int k = 0; k < 64; k++) a = fmaf(hw1[t * 64 + k], p[k], a);
  z[t] = fmaxf(a, 0.f);
  __syncthreads();
  if (t < OUTC) {
    float b = hb2[t];
    #pragma unroll
    for (int k = 0; k < 128; k++) b = fmaf(hw2[t * 128 + k], z[k], b);
    out[g * OUTC + t] = b;
  }
}

extern "C" void kernel_launch(void* const* d_in, const int* in_sizes, int n_in,
                              void* d_out, int out_size, void* d_ws, size_t ws_size,
                              hipStream_t stream) {
  const float* x_f   = (const float*)d_in[0];
  const int*   ei    = (const int*)d_in[1];
  const float* eattr = (const float*)d_in[2];
  const int*   batch = (const int*)d_in[3];
  const float* l0_ew = (const float*)d_in[4];
  const float* l0_eb = (const float*)d_in[5];
  const float* l0_w1 = (const float*)d_in[6];
  const float* l0_b1 = (const float*)d_in[7];
  const float* l0_w2 = (const float*)d_in[8];
  const float* l0_b2 = (const float*)d_in[9];
  const float* ew    = (const float*)d_in[10];
  const float* eb    = (const float*)d_in[11];
  const float* w1    = (const float*)d_in[12];
  const float* b1    = (const float*)d_in[13];
  const float* w2    = (const float*)d_in[14];
  const float* b2    = (const float*)d_in[15];
  const float* bng   = (const float*)d_in[16];
  const float* bnb   = (const float*)d_in[17];
  const float* hw1   = (const float*)d_in[18];
  const float* hb1   = (const float*)d_in[19];
  const float* hw2   = (const float*)d_in[20];
  const float* hb2   = (const float*)d_in[21];
  const int* esrc = ei;
  const int* edst = ei + NE;

  char* wsb = (char*)d_ws;
  size_t off = 0;
  auto A = [&](size_t bytes) -> void* {
    void* p = wsb + off;
    off = (off + bytes + 255) & ~(size_t)255;
    return p;
  };
  int*   csrc = (int*)A((size_t)NE * 4);
  int*   ceid = (int*)A((size_t)NE * 4);
  int*   offs = (int*)A((size_t)NN * 4);
  int*   deg  = (int*)A((size_t)NN * 4);
  int*   cur  = (int*)A((size_t)NN * 4);
  int*   bsum = (int*)A(128 * 4);
  int*   gst  = (int*)A((NG + 1) * 4);
  float* hpre = (float*)A((size_t)NN * 64 * 4);
  float* h2   = (float*)A((size_t)NN * 64 * 4);
  float* bnsq = (float*)A(4 * 128 * 4);   // [layer][sum64|sq64]
  float* scs  = (float*)A(4 * 64 * 4);
  float* shs  = (float*)A(4 * 64 * 4);
  float* pooled = (float*)A((size_t)NG * 64 * 4);
  float* w2t  = (float*)A(4 * 4096 * 4);
  float* eperm = (float*)A((size_t)NE * 16 * 4);  // 102.4 MB, optional
  const int doPerm = (ws_size >= off) ? 1 : 0;    // stable across calls -> graph-safe

  hipMemsetAsync(deg, 0, (size_t)NN * 4, stream);
  hipMemsetAsync(bnsq, 0, 4 * 128 * 4, stream);
  hipMemsetAsync(pooled, 0, (size_t)NG * 64 * 4, stream);

  k_tr<<<64, 256, 0, stream>>>(l0_w2, w2, w2t);
  k_gstart<<<(NN + 255) / 256, 256, 0, stream>>>(batch, gst);

  k_deg<<<(NE + 255) / 256, 256, 0, stream>>>(edst, deg);
  k_scan1<<<98, 1024, 0, stream>>>(deg, offs, bsum);
  k_scan2<<<1, 128, 0, stream>>>(bsum, 98);
  k_scan3<<<(NN + 255) / 256, 256, 0, stream>>>(offs, bsum, cur);
  k_fill<<<(NE + 255) / 256, 256, 0, stream>>>(esrc, edst, cur, csrc, ceid,
                                               (const float4*)eattr, (float4*)eperm, doPerm);

  const int nodeBlocks = (NN * 64 + 255) / 256;
  const int rowBlocks = (NN + 255) / 256;
  const float* eatt_use = doPerm ? eperm : eattr;

  // ---- layer 0 ----
  if (doPerm)
    k_edgeB<32, false, true><<<nodeBlocks, 256, 0, stream>>>(csrc, ceid, offs, deg, x_f,
                                                             nullptr, nullptr, eatt_use, l0_ew, l0_eb, hpre);
  else
    k_edgeB<32, false, false><<<nodeBlocks, 256, 0, stream>>>(csrc, ceid, offs, deg, x_f,
                                                              nullptr, nullptr, eatt_use, l0_ew, l0_eb, hpre);
  k_mlp<32><<<rowBlocks, 256, 0, stream>>>(hpre, l0_w1, l0_b1, w2t, l0_b2, h2, bnsq + 0);
  k_bnfin<<<1, 64, 0, stream>>>(bnsq, bng, bnb, 0, scs, shs);

  // ---- layers 1..3: gather from h2 with fused BN(prev)+relu ----
  for (int i = 0; i < 3; i++) {
    if (doPerm)
      k_edgeB<64, true, true><<<nodeBlocks, 256, 0, stream>>>(csrc, ceid, offs, deg, h2,
                                                              scs + i * 64, shs + i * 64, eatt_use,
                                                              ew + (size_t)i * 1024, eb + (size_t)i * 64, hpre);
    else
      k_edgeB<64, true, false><<<nodeBlocks, 256, 0, stream>>>(csrc, ceid, offs, deg, h2,
                                                               scs + i * 64, shs + i * 64, eatt_use,
                                                               ew + (size_t)i * 1024, eb + (size_t)i * 64, hpre);
    k_mlp<64><<<rowBlocks, 256, 0, stream>>>(hpre, w1 + (size_t)i * 4096, b1 + (size_t)i * 64,
                                             w2t + (size_t)(i + 1) * 4096, b2 + (size_t)i * 64,
                                             h2, bnsq + (i + 1) * 128);
    k_bnfin<<<1, 64, 0, stream>>>(bnsq, bng, bnb, i + 1, scs, shs);
  }

  // ---- pool (applies BN layer 3) + head ----
  k_pool2<<<NG * 4, 256, 0, stream>>>(h2, scs + 3 * 64, shs + 3 * 64, gst, pooled);
  k_head<<<NG, 128, 0, stream>>>(pooled, gst, hw1, hb1, hw2, hb2, (float*)d_out);
}

// Round 6
// 1395.818 us; speedup vs baseline: 1.7050x; 1.1342x over previous
//
#include <hip/hip_runtime.h>

// Problem constants
#define NN 100000
#define NE 1600000
#define DIN 32
#define DE 16
#define HC 64
#define NL 4
#define MHC 128
#define OUTC 10
#define NG 128

// ---- CSR build ----
__global__ __launch_bounds__(256) void k_deg(const int* __restrict__ dst, int* __restrict__ deg) {
  int e = blockIdx.x * 256 + threadIdx.x;
  if (e < NE) atomicAdd(&deg[dst[e]], 1);
}

__global__ __launch_bounds__(1024) void k_scan1(const int* __restrict__ deg, int* __restrict__ offs, int* __restrict__ bsum) {
  __shared__ int s[1024];
  int t = threadIdx.x;
  int i = blockIdx.x * 1024 + t;
  int v = (i < NN) ? deg[i] : 0;
  s[t] = v; __syncthreads();
  for (int d = 1; d < 1024; d <<= 1) {
    int x = 0;
    if (t >= d) x = s[t - d];
    __syncthreads();
    if (t >= d) s[t] += x;
    __syncthreads();
  }
  if (i < NN) offs[i] = s[t] - v;
  if (t == 1023) bsum[blockIdx.x] = s[t];
}

__global__ __launch_bounds__(128) void k_scan2(int* __restrict__ bsum, int nb) {
  __shared__ int s[128];
  int t = threadIdx.x;
  int v = (t < nb) ? bsum[t] : 0;
  s[t] = v; __syncthreads();
  for (int d = 1; d < 128; d <<= 1) {
    int x = 0;
    if (t >= d) x = s[t - d];
    __syncthreads();
    if (t >= d) s[t] += x;
    __syncthreads();
  }
  if (t < nb) bsum[t] = s[t] - v;
}

// also builds odeg = (start, deg) int2
__global__ __launch_bounds__(256) void k_scan3(int* __restrict__ offs, const int* __restrict__ bsum,
                                               const int* __restrict__ deg,
                                               int* __restrict__ cur, int2* __restrict__ odeg) {
  int i = blockIdx.x * 256 + threadIdx.x;
  if (i < NN) {
    int o = offs[i] + bsum[i >> 10];
    offs[i] = o;
    cur[i] = o;
    odeg[i] = make_int2(o, deg[i]);
  }
}

__global__ __launch_bounds__(256) void k_fill(const int* __restrict__ src, const int* __restrict__ dst,
                                              int* __restrict__ cur, int* __restrict__ csrc, int* __restrict__ ceid,
                                              const float4* __restrict__ eattr4, float4* __restrict__ eperm4,
                                              int doPerm) {
  int e = blockIdx.x * 256 + threadIdx.x;
  if (e < NE) {
    int d = dst[e];
    int pos = atomicAdd(&cur[d], 1);
    csrc[pos] = src[e];
    ceid[pos] = e;
    if (doPerm) {
      float4 a0 = eattr4[(size_t)e * 4 + 0];
      float4 a1 = eattr4[(size_t)e * 4 + 1];
      float4 a2 = eattr4[(size_t)e * 4 + 2];
      float4 a3 = eattr4[(size_t)e * 4 + 3];
      eperm4[(size_t)pos * 4 + 0] = a0;
      eperm4[(size_t)pos * 4 + 1] = a1;
      eperm4[(size_t)pos * 4 + 2] = a2;
      eperm4[(size_t)pos * 4 + 3] = a3;
    }
  }
}

// ---- graph boundaries (batch sorted) ----
__global__ __launch_bounds__(256) void k_gstart(const int* __restrict__ batch, int* __restrict__ gstart) {
  int i = blockIdx.x * 256 + threadIdx.x;
  if (i >= NN) return;
  int b = batch[i];
  int bp = (i == 0) ? -1 : batch[i - 1];
  for (int g = bp + 1; g <= b; g++) gstart[g] = i;
  if (i == NN - 1)
    for (int g = b + 1; g <= NG; g++) gstart[g] = NN;
}

// ---- w2 transpose ----
__global__ __launch_bounds__(256) void k_tr(const float* __restrict__ l0w2, const float* __restrict__ w2,
                                            float* __restrict__ w2t) {
  int id = blockIdx.x * 256 + threadIdx.x;
  int mat = id >> 12;
  int j = id & 4095;
  int c1 = j >> 6, c2 = j & 63;
  const float* s = (mat == 0) ? l0w2 : (w2 + (size_t)(mat - 1) * 4096);
  w2t[mat * 4096 + j] = s[c2 * 64 + c1];
}

// ---- layer-0 padding prep: x -> [N][64] (upper 32 zero), ew0 -> [64][16], eb0 -> [64] ----
__global__ __launch_bounds__(256) void k_prep0(const float* __restrict__ l0ew, const float* __restrict__ l0eb,
                                               float* __restrict__ ew0p, float* __restrict__ eb0p) {
  int i = blockIdx.x * 256 + threadIdx.x;
  if (i < 1024) {
    int cc = i >> 4;
    ew0p[i] = (cc < 32) ? l0ew[i] : 0.f;
  }
  if (i < 64) eb0p[i] = (i < 32) ? l0eb[i] : 0.f;
}

__global__ __launch_bounds__(256) void k_xpad(const float* __restrict__ x, float* __restrict__ xpad) {
  int i = blockIdx.x * 256 + threadIdx.x;   // over NN*64
  if (i >= NN * 64) return;
  int cc = i & 63;
  xpad[i] = (cc < 32) ? x[(size_t)(i >> 6) * 32 + cc] : 0.f;
}

#define EDGE_DOT(el, a0, a1, a2, a3)                              \
  el = fmaf(a0.x, w[0],  el); el = fmaf(a0.y, w[1],  el);         \
  el = fmaf(a0.z, w[2],  el); el = fmaf(a0.w, w[3],  el);         \
  el = fmaf(a1.x, w[4],  el); el = fmaf(a1.y, w[5],  el);         \
  el = fmaf(a1.z, w[6],  el); el = fmaf(a1.w, w[7],  el);         \
  el = fmaf(a2.x, w[8],  el); el = fmaf(a2.y, w[9],  el);         \
  el = fmaf(a2.z, w[10], el); el = fmaf(a2.w, w[11], el);         \
  el = fmaf(a3.x, w[12], el); el = fmaf(a3.y, w[13], el);         \
  el = fmaf(a3.z, w[14], el); el = fmaf(a3.w, w[15], el);

// ---- edge aggregation: wave per node, lane = channel (C=64 always, layer0 padded).
//      eattr via coalesced block load + v_readlane broadcast (no LDS, no VMEM broadcast).
//      16 x-gathers prefetched per chunk. Optional fused BN+relu on gathered x. ----
template<bool BN, bool PERM>
__global__ __launch_bounds__(256) void k_edgeR(
    const int* __restrict__ csrc, const int* __restrict__ ceid, const int2* __restrict__ odeg,
    const float* __restrict__ xsrc, const float* __restrict__ scp, const float* __restrict__ shp,
    const float* __restrict__ eattr,
    const float* __restrict__ ewf, const float* __restrict__ ebf,
    float* __restrict__ hpre)
{
  int gt = blockIdx.x * 256 + threadIdx.x;
  int node = gt >> 6;
  if (node >= NN) return;
  int c = threadIdx.x & 63;
  float w[16];
  {
    const float4* wv = (const float4*)(ewf + c * 16);
    float4 t0 = wv[0], t1 = wv[1], t2 = wv[2], t3 = wv[3];
    w[0]=t0.x; w[1]=t0.y; w[2]=t0.z; w[3]=t0.w;
    w[4]=t1.x; w[5]=t1.y; w[6]=t1.z; w[7]=t1.w;
    w[8]=t2.x; w[9]=t2.y; w[10]=t2.z; w[11]=t2.w;
    w[12]=t3.x; w[13]=t3.y; w[14]=t3.z; w[15]=t3.w;
  }
  float bc = ebf[c];
  float scv = 1.f, shv = 0.f;
  if (BN) { scv = scp[c]; shv = shp[c]; }
  int2 od = odeg[node];
  int start = od.x, n = od.y;
  float acc = 0.f;

  for (int base = 0; base < n; base += 16) {
    int cn = min(16, n - base);
    // src indices for the chunk (lanes 0..cn-1)
    int sidx = 0;
    if (c < cn) sidx = csrc[start + base + c];
    // coalesced eattr block loads: each covers 4 edges (64 dwords); lane ll holds dword ll.
    unsigned ead[4];
    if (PERM) {
      #pragma unroll
      for (int j = 0; j < 4; j++) {
        if (base + 4 * j < n)
          ead[j] = ((const unsigned*)eattr)[(size_t)(start + base + 4 * j) * 16 + c];
      }
    }
    // prefetch all x-gathers for the chunk
    float xv[16];
    #pragma unroll
    for (int u = 0; u < 16; u++) {
      if (u < cn) {
        int s = __shfl(sidx, u);
        xv[u] = xsrc[(size_t)s * 64 + c];
      } else xv[u] = 0.f;
    }
    if (PERM) {
      #pragma unroll
      for (int j = 0; j < 4; j++) {
        #pragma unroll
        for (int u2 = 0; u2 < 4; u2++) {
          int u = 4 * j + u2;
          if (u >= cn) break;
          float el = bc;
          #pragma unroll
          for (int t = 0; t < 16; t++) {
            float ev = __uint_as_float((unsigned)__builtin_amdgcn_readlane((int)ead[j], u2 * 16 + t));
            el = fmaf(ev, w[t], el);
          }
          float xs = xv[u];
          if (BN) xs = fmaxf(fmaf(xs, scv, shv), 0.f);
          acc += fmaxf(xs + el, 0.f);
        }
      }
    } else {
      #pragma unroll 4
      for (int u = 0; u < 16; u++) {
        if (u >= cn) break;
        size_t pos = (size_t)ceid[start + base + u];
        const float4* ea = (const float4*)(eattr + pos * 16);
        float4 a0 = ea[0], a1 = ea[1], a2 = ea[2], a3 = ea[3];
        float el = bc;
        EDGE_DOT(el, a0, a1, a2, a3);
        float xs = xv[u];
        if (BN) xs = fmaxf(fmaf(xs, scv, shv), 0.f);
        acc += fmaxf(xs + el, 0.f);
      }
    }
  }

  float xself = xsrc[(size_t)node * 64 + c];
  if (BN) xself = fmaxf(fmaf(xself, scv, shv), 0.f);
  hpre[(size_t)node * 64 + c] = xself + acc;
}

// ---- fused node MLP + BN-stats epilogue; input rows have stride 64 ----
template<int CIN>
__global__ __launch_bounds__(256) void k_mlp(
    const float* __restrict__ hpre,
    const float* __restrict__ w1f, const float* __restrict__ b1f,
    const float* __restrict__ w2tf, const float* __restrict__ b2v,
    float* __restrict__ h2, float* __restrict__ bnsq)
{
  int row0 = blockIdx.x * 256 + threadIdx.x;
  bool act = row0 < NN;
  int row = act ? row0 : (NN - 1);
  float hrow[CIN];
  const float4* hp = (const float4*)(hpre + (size_t)row * 64);
  #pragma unroll
  for (int k = 0; k < CIN / 4; k++) {
    float4 v = hp[k];
    hrow[4*k] = v.x; hrow[4*k+1] = v.y; hrow[4*k+2] = v.z; hrow[4*k+3] = v.w;
  }
  float acc2[64];
  #pragma unroll
  for (int c = 0; c < 64; c++) acc2[c] = b2v[c];
  #pragma unroll 4
  for (int c1 = 0; c1 < 64; c1++) {
    float a = b1f[c1];
    #pragma unroll
    for (int k = 0; k < CIN; k++) a = fmaf(w1f[c1 * CIN + k], hrow[k], a);
    a = fmaxf(a, 0.f);
    #pragma unroll
    for (int c2 = 0; c2 < 64; c2++) acc2[c2] = fmaf(w2tf[c1 * 64 + c2], a, acc2[c2]);
  }
  #pragma unroll
  for (int c = 0; c < 64; c++) acc2[c] = fmaxf(acc2[c], 0.f);
  if (act) {
    float4* out = (float4*)(h2 + (size_t)row * 64);
    #pragma unroll
    for (int q = 0; q < 16; q++)
      out[q] = make_float4(acc2[4*q], acc2[4*q+1], acc2[4*q+2], acc2[4*q+3]);
  } else {
    #pragma unroll
    for (int c = 0; c < 64; c++) acc2[c] = 0.f;
  }
  __shared__ float part[4][128];
  int wid = threadIdx.x >> 6, lane = threadIdx.x & 63;
  #pragma unroll
  for (int c = 0; c < 64; c++) {
    float s = acc2[c], q = s * s;
    #pragma unroll
    for (int m = 1; m < 64; m <<= 1) { s += __shfl_xor(s, m); q += __shfl_xor(q, m); }
    if (lane == 0) { part[wid][c] = s; part[wid][64 + c] = q; }
  }
  __syncthreads();
  if (threadIdx.x < 128) {
    float v = part[0][threadIdx.x] + part[1][threadIdx.x] + part[2][threadIdx.x] + part[3][threadIdx.x];
    atomicAdd(&bnsq[threadIdx.x], v);
  }
}

__global__ __launch_bounds__(64) void k_bnfin(const float* __restrict__ bnsq,
                                              const float* __restrict__ gamma, const float* __restrict__ beta,
                                              int layer, float* __restrict__ scs, float* __restrict__ shs) {
  int c = threadIdx.x;
  if (c >= 64) return;
  const float* sl = bnsq + layer * 128;
  float mu = sl[c] * (1.0f / NN);
  float var = sl[64 + c] * (1.0f / NN) - mu * mu;
  float r = rsqrtf(var + 1e-5f);
  float s = gamma[layer * 64 + c] * r;
  scs[layer * 64 + c] = s;
  shs[layer * 64 + c] = beta[layer * 64 + c] - mu * s;
}

// ---- pool: BN+relu on the fly; batch sorted -> contiguous ranges ----
__global__ __launch_bounds__(256) void k_pool2(const float* __restrict__ h2, const float* __restrict__ sc,
                                               const float* __restrict__ sh, const int* __restrict__ gstart,
                                               float* __restrict__ pooled) {
  int g = blockIdx.x >> 2, sub = blockIdx.x & 3;
  int s = gstart[g], e = gstart[g + 1];
  int c = threadIdx.x & 63, rg = threadIdx.x >> 6;
  float scv = sc[c], shv = sh[c];
  float acc = 0.f;
  for (int r = s + sub * 4 + rg; r < e; r += 16)
    acc += fmaxf(fmaf(h2[(size_t)r * 64 + c], scv, shv), 0.f);
  __shared__ float ls[256];
  ls[threadIdx.x] = acc;
  __syncthreads();
  if (rg == 0) {
    float v = ls[c] + ls[64 + c] + ls[128 + c] + ls[192 + c];
    atomicAdd(&pooled[g * 64 + c], v);
  }
}

__global__ __launch_bounds__(128) void k_head(const float* __restrict__ pooled, const int* __restrict__ gstart,
                                              const float* __restrict__ hw1, const float* __restrict__ hb1,
                                              const float* __restrict__ hw2, const float* __restrict__ hb2,
                                              float* __restrict__ out) {
  __shared__ float p[64];
  __shared__ float z[128];
  int g = blockIdx.x, t = threadIdx.x;
  if (t < 64) {
    int cn = gstart[g + 1] - gstart[g];
    float inv = 1.0f / (float)(cn > 0 ? cn : 1);
    p[t] = pooled[g * 64 + t] * inv;
  }
  __syncthreads();
  float a = hb1[t];
  #pragma unroll
  for (int k = 0; k < 64; k++) a = fmaf(hw1[t * 64 + k], p[k], a);
  z[t] = fmaxf(a, 0.f);
  __syncthreads();
  if (t < OUTC) {
    float b = hb2[t];
    #pragma unroll
    for (int k = 0; k < 128; k++) b = fmaf(hw2[t * 128 + k], z[k], b);
    out[g * OUTC + t] = b;
  }
}

extern "C" void kernel_launch(void* const* d_in, const int* in_sizes, int n_in,
                              void* d_out, int out_size, void* d_ws, size_t ws_size,
                              hipStream_t stream) {
  const float* x_f   = (const float*)d_in[0];
  const int*   ei    = (const int*)d_in[1];
  const float* eattr = (const float*)d_in[2];
  const int*   batch = (const int*)d_in[3];
  const float* l0_ew = (const float*)d_in[4];
  const float* l0_eb = (const float*)d_in[5];
  const float* l0_w1 = (const float*)d_in[6];
  const float* l0_b1 = (const float*)d_in[7];
  const float* l0_w2 = (const float*)d_in[8];
  const float* l0_b2 = (const float*)d_in[9];
  const float* ew    = (const float*)d_in[10];
  const float* eb    = (const float*)d_in[11];
  const float* w1    = (const float*)d_in[12];
  const float* b1    = (const float*)d_in[13];
  const float* w2    = (const float*)d_in[14];
  const float* b2    = (const float*)d_in[15];
  const float* bng   = (const float*)d_in[16];
  const float* bnb   = (const float*)d_in[17];
  const float* hw1   = (const float*)d_in[18];
  const float* hb1   = (const float*)d_in[19];
  const float* hw2   = (const float*)d_in[20];
  const float* hb2   = (const float*)d_in[21];
  const int* esrc = ei;
  const int* edst = ei + NE;

  char* wsb = (char*)d_ws;
  size_t off = 0;
  auto A = [&](size_t bytes) -> void* {
    void* p = wsb + off;
    off = (off + bytes + 255) & ~(size_t)255;
    return p;
  };
  int*   csrc = (int*)A((size_t)NE * 4);
  int*   ceid = (int*)A((size_t)NE * 4);
  int*   offs = (int*)A((size_t)NN * 4);
  int*   deg  = (int*)A((size_t)NN * 4);
  int*   cur  = (int*)A((size_t)NN * 4);
  int2*  odeg = (int2*)A((size_t)NN * 8);
  int*   bsum = (int*)A(128 * 4);
  int*   gst  = (int*)A((NG + 1) * 4);
  float* xpad = (float*)A((size_t)NN * 64 * 4);
  float* hpre = (float*)A((size_t)NN * 64 * 4);
  float* h2   = (float*)A((size_t)NN * 64 * 4);
  float* bnsq = (float*)A(4 * 128 * 4);   // [layer][sum64|sq64]
  float* scs  = (float*)A(4 * 64 * 4);
  float* shs  = (float*)A(4 * 64 * 4);
  float* pooled = (float*)A((size_t)NG * 64 * 4);
  float* w2t  = (float*)A(4 * 4096 * 4);
  float* ew0p = (float*)A(1024 * 4);
  float* eb0p = (float*)A(64 * 4);
  float* eperm = (float*)A(((size_t)NE + 16) * 16 * 4);  // +16 edges pad for block over-read
  const int doPerm = (ws_size >= off) ? 1 : 0;           // stable across calls -> graph-safe

  hipMemsetAsync(deg, 0, (size_t)NN * 4, stream);
  hipMemsetAsync(bnsq, 0, 4 * 128 * 4, stream);
  hipMemsetAsync(pooled, 0, (size_t)NG * 64 * 4, stream);

  k_tr<<<64, 256, 0, stream>>>(l0_w2, w2, w2t);
  k_prep0<<<4, 256, 0, stream>>>(l0_ew, l0_eb, ew0p, eb0p);
  k_xpad<<<(NN * 64 + 255) / 256, 256, 0, stream>>>(x_f, xpad);
  k_gstart<<<(NN + 255) / 256, 256, 0, stream>>>(batch, gst);

  k_deg<<<(NE + 255) / 256, 256, 0, stream>>>(edst, deg);
  k_scan1<<<98, 1024, 0, stream>>>(deg, offs, bsum);
  k_scan2<<<1, 128, 0, stream>>>(bsum, 98);
  k_scan3<<<(NN + 255) / 256, 256, 0, stream>>>(offs, bsum, deg, cur, odeg);
  k_fill<<<(NE + 255) / 256, 256, 0, stream>>>(esrc, edst, cur, csrc, ceid,
                                               (const float4*)eattr, (float4*)eperm, doPerm);

  const int nodeBlocks = (NN * 64 + 255) / 256;
  const int rowBlocks = (NN + 255) / 256;
  const float* eatt_use = doPerm ? eperm : eattr;

  // ---- layer 0 (padded to C=64; BN=false) ----
  if (doPerm)
    k_edgeR<false, true><<<nodeBlocks, 256, 0, stream>>>(csrc, ceid, odeg, xpad,
                                                         nullptr, nullptr, eatt_use, ew0p, eb0p, hpre);
  else
    k_edgeR<false, false><<<nodeBlocks, 256, 0, stream>>>(csrc, ceid, odeg, xpad,
                                                          nullptr, nullptr, eatt_use, ew0p, eb0p, hpre);
  k_mlp<32><<<rowBlocks, 256, 0, stream>>>(hpre, l0_w1, l0_b1, w2t, l0_b2, h2, bnsq + 0);
  k_bnfin<<<1, 64, 0, stream>>>(bnsq, bng, bnb, 0, scs, shs);

  // ---- layers 1..3: gather from h2 with fused BN(prev)+relu ----
  for (int i = 0; i < 3; i++) {
    if (doPerm)
      k_edgeR<true, true><<<nodeBlocks, 256, 0, stream>>>(csrc, ceid, odeg, h2,
                                                          scs + i * 64, shs + i * 64, eatt_use,
                                                          ew + (size_t)i * 1024, eb + (size_t)i * 64, hpre);
    else
      k_edgeR<true, false><<<nodeBlocks, 256, 0, stream>>>(csrc, ceid, odeg, h2,
                                                           scs + i * 64, shs + i * 64, eatt_use,
                                                           ew + (size_t)i * 1024, eb + (size_t)i * 64, hpre);
    k_mlp<64><<<rowBlocks, 256, 0, stream>>>(hpre, w1 + (size_t)i * 4096, b1 + (size_t)i * 64,
                                             w2t + (size_t)(i + 1) * 4096, b2 + (size_t)i * 64,
                                             h2, bnsq + (i + 1) * 128);
    k_bnfin<<<1, 64, 0, stream>>>(bnsq, bng, bnb, i + 1, scs, shs);
  }

  // ---- pool (applies BN layer 3) + head ----
  k_pool2<<<NG * 4, 256, 0, stream>>>(h2, scs + 3 * 64, shs + 3 * 64, gst, pooled);
  k_head<<<NG, 128, 0, stream>>>(pooled, gst, hw1, hb1, hw2, hb2, (float*)d_out);
}

// Round 7
// 1376.175 us; speedup vs baseline: 1.7293x; 1.0143x over previous
//
#include <hip/hip_runtime.h>
#include <hip/hip_fp16.h>

// Problem constants
#define NN 100000
#define NE 1600000
#define DIN 32
#define DE 16
#define HC 64
#define NL 4
#define MHC 128
#define OUTC 10
#define NG 128

typedef _Float16 half2_t __attribute__((ext_vector_type(2)));

__device__ __forceinline__ float dot2f(unsigned pv, half2_t w2, float acc) {
#if __has_builtin(__builtin_amdgcn_fdot2)
  return __builtin_amdgcn_fdot2(__builtin_bit_cast(half2_t, pv), w2, acc, false);
#else
  __half2 h = *(__half2*)&pv; __half2 ww = *(__half2*)&w2;
  return acc + __low2float(h) * __low2float(ww) + __high2float(h) * __high2float(ww);
#endif
}

// ---- CSR build ----
__global__ __launch_bounds__(256) void k_deg(const int* __restrict__ dst, int* __restrict__ deg) {
  int e = blockIdx.x * 256 + threadIdx.x;
  if (e < NE) atomicAdd(&deg[dst[e]], 1);
}

__global__ __launch_bounds__(1024) void k_scan1(const int* __restrict__ deg, int* __restrict__ offs, int* __restrict__ bsum) {
  __shared__ int s[1024];
  int t = threadIdx.x;
  int i = blockIdx.x * 1024 + t;
  int v = (i < NN) ? deg[i] : 0;
  s[t] = v; __syncthreads();
  for (int d = 1; d < 1024; d <<= 1) {
    int x = 0;
    if (t >= d) x = s[t - d];
    __syncthreads();
    if (t >= d) s[t] += x;
    __syncthreads();
  }
  if (i < NN) offs[i] = s[t] - v;
  if (t == 1023) bsum[blockIdx.x] = s[t];
}

__global__ __launch_bounds__(128) void k_scan2(int* __restrict__ bsum, int nb) {
  __shared__ int s[128];
  int t = threadIdx.x;
  int v = (t < nb) ? bsum[t] : 0;
  s[t] = v; __syncthreads();
  for (int d = 1; d < 128; d <<= 1) {
    int x = 0;
    if (t >= d) x = s[t - d];
    __syncthreads();
    if (t >= d) s[t] += x;
    __syncthreads();
  }
  if (t < nb) bsum[t] = s[t] - v;
}

// also builds odeg = (start, deg) int2
__global__ __launch_bounds__(256) void k_scan3(int* __restrict__ offs, const int* __restrict__ bsum,
                                               const int* __restrict__ deg,
                                               int* __restrict__ cur, int2* __restrict__ odeg) {
  int i = blockIdx.x * 256 + threadIdx.x;
  if (i < NN) {
    int o = offs[i] + bsum[i >> 10];
    offs[i] = o;
    cur[i] = o;
    odeg[i] = make_int2(o, deg[i]);
  }
}

__global__ __launch_bounds__(256) void k_fill(const int* __restrict__ src, const int* __restrict__ dst,
                                              int* __restrict__ cur, int* __restrict__ csrc, int* __restrict__ ceid) {
  int e = blockIdx.x * 256 + threadIdx.x;
  if (e < NE) {
    int d = dst[e];
    int pos = atomicAdd(&cur[d], 1);
    csrc[pos] = src[e];
    ceid[pos] = e;
  }
}

// ---- gather-cast: eattr (f32, original order) -> e16 (f16-packed, CSR order) ----
__global__ __launch_bounds__(256) void k_cast(const int* __restrict__ ceid,
                                              const float4* __restrict__ eattr4,
                                              uint4* __restrict__ e16) {
  int p = blockIdx.x * 256 + threadIdx.x;
  if (p >= NE) return;
  int e = ceid[p];
  float4 a0 = eattr4[(size_t)e * 4 + 0];
  float4 a1 = eattr4[(size_t)e * 4 + 1];
  float4 a2 = eattr4[(size_t)e * 4 + 2];
  float4 a3 = eattr4[(size_t)e * 4 + 3];
  __half2 h0 = __floats2half2_rn(a0.x, a0.y), h1 = __floats2half2_rn(a0.z, a0.w);
  __half2 h2 = __floats2half2_rn(a1.x, a1.y), h3 = __floats2half2_rn(a1.z, a1.w);
  __half2 h4 = __floats2half2_rn(a2.x, a2.y), h5 = __floats2half2_rn(a2.z, a2.w);
  __half2 h6 = __floats2half2_rn(a3.x, a3.y), h7 = __floats2half2_rn(a3.z, a3.w);
  uint4 o0 = make_uint4(*(unsigned*)&h0, *(unsigned*)&h1, *(unsigned*)&h2, *(unsigned*)&h3);
  uint4 o1 = make_uint4(*(unsigned*)&h4, *(unsigned*)&h5, *(unsigned*)&h6, *(unsigned*)&h7);
  e16[(size_t)p * 2 + 0] = o0;
  e16[(size_t)p * 2 + 1] = o1;
}

// ---- edge weights -> f16 pairs [4 layers][64 ch][8 dwords] + padded biases [4][64] ----
__global__ __launch_bounds__(256) void k_wprep(const float* __restrict__ l0ew, const float* __restrict__ l0eb,
                                               const float* __restrict__ ew, const float* __restrict__ eb,
                                               unsigned* __restrict__ ewh, float* __restrict__ ebp) {
  int i = blockIdx.x * 256 + threadIdx.x;
  if (i < 2048) {
    int L = i >> 9, r = i & 511;
    int c = r >> 3, t = r & 7;
    float a, b;
    if (L == 0) {
      a = (c < 32) ? l0ew[c * 16 + 2 * t] : 0.f;
      b = (c < 32) ? l0ew[c * 16 + 2 * t + 1] : 0.f;
    } else {
      a = ew[(size_t)(L - 1) * 1024 + c * 16 + 2 * t];
      b = ew[(size_t)(L - 1) * 1024 + c * 16 + 2 * t + 1];
    }
    __half2 h = __floats2half2_rn(a, b);
    ewh[i] = *(unsigned*)&h;
  }
  if (i < 256) {
    int L = i >> 6, c = i & 63;
    ebp[i] = (L == 0) ? ((c < 32) ? l0eb[c] : 0.f) : eb[(size_t)(L - 1) * 64 + c];
  }
}

// ---- graph boundaries (batch sorted) ----
__global__ __launch_bounds__(256) void k_gstart(const int* __restrict__ batch, int* __restrict__ gstart) {
  int i = blockIdx.x * 256 + threadIdx.x;
  if (i >= NN) return;
  int b = batch[i];
  int bp = (i == 0) ? -1 : batch[i - 1];
  for (int g = bp + 1; g <= b; g++) gstart[g] = i;
  if (i == NN - 1)
    for (int g = b + 1; g <= NG; g++) gstart[g] = NN;
}

// ---- w2 transpose ----
__global__ __launch_bounds__(256) void k_tr(const float* __restrict__ l0w2, const float* __restrict__ w2,
                                            float* __restrict__ w2t) {
  int id = blockIdx.x * 256 + threadIdx.x;
  int mat = id >> 12;
  int j = id & 4095;
  int c1 = j >> 6, c2 = j & 63;
  const float* s = (mat == 0) ? l0w2 : (w2 + (size_t)(mat - 1) * 4096);
  w2t[mat * 4096 + j] = s[c2 * 64 + c1];
}

__global__ __launch_bounds__(256) void k_xpad(const float* __restrict__ x, float* __restrict__ xpad) {
  int i = blockIdx.x * 256 + threadIdx.x;   // over NN*64
  if (i >= NN * 64) return;
  int cc = i & 63;
  xpad[i] = (cc < 32) ? x[(size_t)(i >> 6) * 32 + cc] : 0.f;
}

// ---- edge aggregation: wave per node, lane = channel; CSR-ordered f16 eattr via
//      coalesced block load (8 edges/load) + readlane pairs + fdot2.
//      16 x-gathers prefetched per chunk. Optional fused BN+relu on gathered x. ----
template<bool BN>
__global__ __launch_bounds__(256) void k_edgeH(
    const int* __restrict__ csrc, const int2* __restrict__ odeg,
    const float* __restrict__ xsrc, const float* __restrict__ scp, const float* __restrict__ shp,
    const unsigned* __restrict__ e16,
    const unsigned* __restrict__ ewh, const float* __restrict__ ebf,
    float* __restrict__ hpre)
{
  int gt = blockIdx.x * 256 + threadIdx.x;
  int node = gt >> 6;
  if (node >= NN) return;
  int c = threadIdx.x & 63;
  half2_t wh[8];
  {
    const uint4* wv = (const uint4*)(ewh + (size_t)c * 8);
    uint4 q0 = wv[0], q1 = wv[1];
    wh[0] = __builtin_bit_cast(half2_t, q0.x); wh[1] = __builtin_bit_cast(half2_t, q0.y);
    wh[2] = __builtin_bit_cast(half2_t, q0.z); wh[3] = __builtin_bit_cast(half2_t, q0.w);
    wh[4] = __builtin_bit_cast(half2_t, q1.x); wh[5] = __builtin_bit_cast(half2_t, q1.y);
    wh[6] = __builtin_bit_cast(half2_t, q1.z); wh[7] = __builtin_bit_cast(half2_t, q1.w);
  }
  float bcv = ebf[c];
  float scv = 1.f, shv = 0.f;
  if (BN) { scv = scp[c]; shv = shp[c]; }
  int2 od = odeg[node];
  int start = od.x, n = od.y;
  float acc = 0.f;

  for (int base = 0; base < n; base += 16) {
    int cn = min(16, n - base);
    // src indices for the chunk (lanes 0..cn-1)
    int sidx = 0;
    if (c < cn) sidx = csrc[start + base + c];
    // coalesced f16 eattr block loads: one load = 8 edges (64 dwords); lane c holds dword c
    unsigned ead0 = e16[(size_t)(start + base) * 8 + c];
    unsigned ead1 = 0;
    if (cn > 8) ead1 = e16[(size_t)(start + base + 8) * 8 + c];
    // prefetch all x-gathers for the chunk
    float xv[16];
    #pragma unroll
    for (int u = 0; u < 16; u++) {
      if (u < cn) {
        int s = __shfl(sidx, u);
        xv[u] = xsrc[(size_t)s * 64 + c];
      } else xv[u] = 0.f;
    }
    #pragma unroll
    for (int u = 0; u < 16; u++) {
      if (u >= cn) break;
      unsigned eb_ = (u < 8) ? ead0 : ead1;
      int u2 = u & 7;
      float el = bcv;
      #pragma unroll
      for (int t = 0; t < 8; t++) {
        unsigned pv = (unsigned)__builtin_amdgcn_readlane((int)eb_, u2 * 8 + t);
        el = dot2f(pv, wh[t], el);
      }
      float xs = xv[u];
      if (BN) xs = fmaxf(fmaf(xs, scv, shv), 0.f);
      acc += fmaxf(xs + el, 0.f);
    }
  }

  float xself = xsrc[(size_t)node * 64 + c];
  if (BN) xself = fmaxf(fmaf(xself, scv, shv), 0.f);
  hpre[(size_t)node * 64 + c] = xself + acc;
}

// ---- fused node MLP + BN-stats epilogue; input rows have stride 64 ----
template<int CIN>
__global__ __launch_bounds__(256) void k_mlp(
    const float* __restrict__ hpre,
    const float* __restrict__ w1f, const float* __restrict__ b1f,
    const float* __restrict__ w2tf, const float* __restrict__ b2v,
    float* __restrict__ h2, float* __restrict__ bnsq)
{
  int row0 = blockIdx.x * 256 + threadIdx.x;
  bool act = row0 < NN;
  int row = act ? row0 : (NN - 1);
  float hrow[CIN];
  const float4* hp = (const float4*)(hpre + (size_t)row * 64);
  #pragma unroll
  for (int k = 0; k < CIN / 4; k++) {
    float4 v = hp[k];
    hrow[4*k] = v.x; hrow[4*k+1] = v.y; hrow[4*k+2] = v.z; hrow[4*k+3] = v.w;
  }
  float acc2[64];
  #pragma unroll
  for (int c = 0; c < 64; c++) acc2[c] = b2v[c];
  #pragma unroll 4
  for (int c1 = 0; c1 < 64; c1++) {
    float a = b1f[c1];
    #pragma unroll
    for (int k = 0; k < CIN; k++) a = fmaf(w1f[c1 * CIN + k], hrow[k], a);
    a = fmaxf(a, 0.f);
    #pragma unroll
    for (int c2 = 0; c2 < 64; c2++) acc2[c2] = fmaf(w2tf[c1 * 64 + c2], a, acc2[c2]);
  }
  #pragma unroll
  for (int c = 0; c < 64; c++) acc2[c] = fmaxf(acc2[c], 0.f);
  if (act) {
    float4* out = (float4*)(h2 + (size_t)row * 64);
    #pragma unroll
    for (int q = 0; q < 16; q++)
      out[q] = make_float4(acc2[4*q], acc2[4*q+1], acc2[4*q+2], acc2[4*q+3]);
  } else {
    #pragma unroll
    for (int c = 0; c < 64; c++) acc2[c] = 0.f;
  }
  __shared__ float part[4][128];
  int wid = threadIdx.x >> 6, lane = threadIdx.x & 63;
  #pragma unroll
  for (int c = 0; c < 64; c++) {
    float s = acc2[c], q = s * s;
    #pragma unroll
    for (int m = 1; m < 64; m <<= 1) { s += __shfl_xor(s, m); q += __shfl_xor(q, m); }
    if (lane == 0) { part[wid][c] = s; part[wid][64 + c] = q; }
  }
  __syncthreads();
  if (threadIdx.x < 128) {
    float v = part[0][threadIdx.x] + part[1][threadIdx.x] + part[2][threadIdx.x] + part[3][threadIdx.x];
    atomicAdd(&bnsq[threadIdx.x], v);
  }
}

__global__ __launch_bounds__(64) void k_bnfin(const float* __restrict__ bnsq,
                                              const float* __restrict__ gamma, const float* __restrict__ beta,
                                              int layer, float* __restrict__ scs, float* __restrict__ shs) {
  int c = threadIdx.x;
  if (c >= 64) return;
  const float* sl = bnsq + layer * 128;
  float mu = sl[c] * (1.0f / NN);
  float var = sl[64 + c] * (1.0f / NN) - mu * mu;
  float r = rsqrtf(var + 1e-5f);
  float s = gamma[layer * 64 + c] * r;
  scs[layer * 64 + c] = s;
  shs[layer * 64 + c] = beta[layer * 64 + c] - mu * s;
}

// ---- pool: BN+relu on the fly; batch sorted -> contiguous ranges ----
__global__ __launch_bounds__(256) void k_pool2(const float* __restrict__ h2, const float* __restrict__ sc,
                                               const float* __restrict__ sh, const int* __restrict__ gstart,
                                               float* __restrict__ pooled) {
  int g = blockIdx.x >> 2, sub = blockIdx.x & 3;
  int s = gstart[g], e = gstart[g + 1];
  int c = threadIdx.x & 63, rg = threadIdx.x >> 6;
  float scv = sc[c], shv = sh[c];
  float acc = 0.f;
  for (int r = s + sub * 4 + rg; r < e; r += 16)
    acc += fmaxf(fmaf(h2[(size_t)r * 64 + c], scv, shv), 0.f);
  __shared__ float ls[256];
  ls[threadIdx.x] = acc;
  __syncthreads();
  if (rg == 0) {
    float v = ls[c] + ls[64 + c] + ls[128 + c] + ls[192 + c];
    atomicAdd(&pooled[g * 64 + c], v);
  }
}

__global__ __launch_bounds__(128) void k_head(const float* __restrict__ pooled, const int* __restrict__ gstart,
                                              const float* __restrict__ hw1, const float* __restrict__ hb1,
                                              const float* __restrict__ hw2, const float* __restrict__ hb2,
                                              float* __restrict__ out) {
  __shared__ float p[64];
  __shared__ float z[128];
  int g = blockIdx.x, t = threadIdx.x;
  if (t < 64) {
    int cn = gstart[g + 1] - gstart[g];
    float inv = 1.0f / (float)(cn > 0 ? cn : 1);
    p[t] = pooled[g * 64 + t] * inv;
  }
  __syncthreads();
  float a = hb1[t];
  #pragma unroll
  for (int k = 0; k < 64; k++) a = fmaf(hw1[t * 64 + k], p[k], a);
  z[t] = fmaxf(a, 0.f);
  __syncthreads();
  if (t < OUTC) {
    float b = hb2[t];
    #pragma unroll
    for (int k = 0; k < 128; k++) b = fmaf(hw2[t * 128 + k], z[k], b);
    out[g * OUTC + t] = b;
  }
}

extern "C" void kernel_launch(void* const* d_in, const int* in_sizes, int n_in,
                              void* d_out, int out_size, void* d_ws, size_t ws_size,
                              hipStream_t stream) {
  const float* x_f   = (const float*)d_in[0];
  const int*   ei    = (const int*)d_in[1];
  const float* eattr = (const float*)d_in[2];
  const int*   batch = (const int*)d_in[3];
  const float* l0_ew = (const float*)d_in[4];
  const float* l0_eb = (const float*)d_in[5];
  const float* l0_w1 = (const float*)d_in[6];
  const float* l0_b1 = (const float*)d_in[7];
  const float* l0_w2 = (const float*)d_in[8];
  const float* l0_b2 = (const float*)d_in[9];
  const float* ew    = (const float*)d_in[10];
  const float* eb    = (const float*)d_in[11];
  const float* w1    = (const float*)d_in[12];
  const float* b1    = (const float*)d_in[13];
  const float* w2    = (const float*)d_in[14];
  const float* b2    = (const float*)d_in[15];
  const float* bng   = (const float*)d_in[16];
  const float* bnb   = (const float*)d_in[17];
  const float* hw1   = (const float*)d_in[18];
  const float* hb1   = (const float*)d_in[19];
  const float* hw2   = (const float*)d_in[20];
  const float* hb2   = (const float*)d_in[21];
  const int* esrc = ei;
  const int* edst = ei + NE;

  char* wsb = (char*)d_ws;
  size_t off = 0;
  auto A = [&](size_t bytes) -> void* {
    void* p = wsb + off;
    off = (off + bytes + 255) & ~(size_t)255;
    return p;
  };
  int*   csrc = (int*)A((size_t)NE * 4);
  int*   ceid = (int*)A((size_t)NE * 4);
  int*   offs = (int*)A((size_t)NN * 4);
  int*   deg  = (int*)A((size_t)NN * 4);
  int*   cur  = (int*)A((size_t)NN * 4);
  int2*  odeg = (int2*)A((size_t)NN * 8);
  int*   bsum = (int*)A(128 * 4);
  int*   gst  = (int*)A((NG + 1) * 4);
  float* xpad = (float*)A((size_t)NN * 64 * 4);
  float* hpre = (float*)A((size_t)NN * 64 * 4);
  float* h2   = (float*)A((size_t)NN * 64 * 4);
  float* bnsq = (float*)A(4 * 128 * 4);   // [layer][sum64|sq64]
  float* scs  = (float*)A(4 * 64 * 4);
  float* shs  = (float*)A(4 * 64 * 4);
  float* pooled = (float*)A((size_t)NG * 64 * 4);
  float* w2t  = (float*)A(4 * 4096 * 4);
  unsigned* ewh = (unsigned*)A(2048 * 4);   // f16-pair edge weights, 4 layers
  float* ebp  = (float*)A(256 * 4);         // padded edge biases, 4 layers
  unsigned* e16 = (unsigned*)A(((size_t)NE + 16) * 32);  // f16 eattr, CSR order, 8 dwords/edge

  hipMemsetAsync(deg, 0, (size_t)NN * 4, stream);
  hipMemsetAsync(bnsq, 0, 4 * 128 * 4, stream);
  hipMemsetAsync(pooled, 0, (size_t)NG * 64 * 4, stream);

  k_tr<<<64, 256, 0, stream>>>(l0_w2, w2, w2t);
  k_wprep<<<8, 256, 0, stream>>>(l0_ew, l0_eb, ew, eb, ewh, ebp);
  k_xpad<<<(NN * 64 + 255) / 256, 256, 0, stream>>>(x_f, xpad);
  k_gstart<<<(NN + 255) / 256, 256, 0, stream>>>(batch, gst);

  k_deg<<<(NE + 255) / 256, 256, 0, stream>>>(edst, deg);
  k_scan1<<<98, 1024, 0, stream>>>(deg, offs, bsum);
  k_scan2<<<1, 128, 0, stream>>>(bsum, 98);
  k_scan3<<<(NN + 255) / 256, 256, 0, stream>>>(offs, bsum, deg, cur, odeg);
  k_fill<<<(NE + 255) / 256, 256, 0, stream>>>(esrc, edst, cur, csrc, ceid);
  k_cast<<<(NE + 255) / 256, 256, 0, stream>>>(ceid, (const float4*)eattr, (uint4*)e16);

  const int nodeBlocks = (NN * 64 + 255) / 256;
  const int rowBlocks = (NN + 255) / 256;

  // ---- layer 0 (padded to C=64; BN=false) ----
  k_edgeH<false><<<nodeBlocks, 256, 0, stream>>>(csrc, odeg, xpad, nullptr, nullptr,
                                                 e16, ewh, ebp, hpre);
  k_mlp<32><<<rowBlocks, 256, 0, stream>>>(hpre, l0_w1, l0_b1, w2t, l0_b2, h2, bnsq + 0);
  k_bnfin<<<1, 64, 0, stream>>>(bnsq, bng, bnb, 0, scs, shs);

  // ---- layers 1..3: gather from h2 with fused BN(prev)+relu ----
  for (int i = 0; i < 3; i++) {
    k_edgeH<true><<<nodeBlocks, 256, 0, stream>>>(csrc, odeg, h2,
                                                  scs + i * 64, shs + i * 64,
                                                  e16, ewh + (size_t)(i + 1) * 512, ebp + (i + 1) * 64, hpre);
    k_mlp<64><<<rowBlocks, 256, 0, stream>>>(hpre, w1 + (size_t)i * 4096, b1 + (size_t)i * 64,
                                             w2t + (size_t)(i + 1) * 4096, b2 + (size_t)i * 64,
                                             h2, bnsq + (i + 1) * 128);
    k_bnfin<<<1, 64, 0, stream>>>(bnsq, bng, bnb, i + 1, scs, shs);
  }

  // ---- pool (applies BN layer 3) + head ----
  k_pool2<<<NG * 4, 256, 0, stream>>>(h2, scs + 3 * 64, shs + 3 * 64, gst, pooled);
  k_head<<<NG, 128, 0, stream>>>(pooled, gst, hw1, hb1, hw2, hb2, (float*)d_out);
}